// Round 4
// baseline (250.493 us; speedup 1.0000x reference)
//
#include <hip/hip_runtime.h>
#include <hip/hip_bf16.h>

// ---------------------------------------------------------------------------
// MonotonicAlignmentSearch R4: gather-free fused logits+softmax (apT layout),
// direct-epilogue tp GEMM, GN2 folded into conv3. B=2, TT=128, TA=512, H=1024.
// ---------------------------------------------------------------------------

typedef __bf16 bf16_t;
typedef __bf16 bf16x8 __attribute__((ext_vector_type(8)));
typedef __bf16 bf16x4 __attribute__((ext_vector_type(4)));
typedef float  f32x4  __attribute__((ext_vector_type(4)));

#define EPSV 1e-5f

// ---- workspace offsets (bytes) --------------------------------------------
#define OFF_TEXTBF   0u          //  524288  bf16 text [256][1024]
#define OFF_AUDIOBF  524288u     // 2097152  bf16 audio [1024][1024]
#define OFF_W1TOP    2621440u    // 2097152  bf16 W1topT [1024][1024]
#define OFF_W1BOT    4718592u    // 2097152  bf16 W1botT [1024][1024]
#define OFF_WC       0u          // 6291456  bf16 Wc [3][1024][1024] (overlays
                                 //          stage-1 buffers after gemms)
#define OFF_TP       6815744u    // 1048576  f32 tp [256][1024] (bias folded)
#define OFF_APT      7864320u    // 2097152  bf16 apT [1024 h][1024 ba]
#define OFF_XP0      9961472u    //  532480  bf16 xp0 [2][130][1024]
#define OFF_XP1      10493952u   //  532480  bf16 xp1 [2][130][1024]
#define OFF_STATS    11026432u   //      32  8 floats (GN stats)
#define OFF_Y2       11027456u   //  524288  bf16 y2 [256][1024] (pre-GN)
#define OFF_PARTS    11551744u   // 4194304  f32 conv split-k partials
// total 15746048 < 17842208 proven-good

// ---------------------------------------------------------------------------
// prep: fp32 -> bf16 for text (flat + padded xp0) and audio
// ---------------------------------------------------------------------------
__global__ __launch_bounds__(256) void cvt_act_k(
    const float* __restrict__ text, const float* __restrict__ audio,
    bf16_t* __restrict__ text_bf, bf16_t* __restrict__ xp0,
    bf16_t* __restrict__ audio_bf)
{
    const int e = (blockIdx.x * 256 + threadIdx.x) * 4;   // 1310720 total
    if (e < 262144) {
        float4 v = *(const float4*)&text[e];
        bf16x4 o; o[0] = (bf16_t)v.x; o[1] = (bf16_t)v.y; o[2] = (bf16_t)v.z; o[3] = (bf16_t)v.w;
        *(bf16x4*)&text_bf[e] = o;
        const int bt = e >> 10, h = e & 1023;
        const int b = bt >> 7, t = bt & 127;
        *(bf16x4*)&xp0[(size_t)(b * 130 + 1 + t) * 1024 + h] = o;
    } else {
        const int ea = e - 262144;
        float4 v = *(const float4*)&audio[ea];
        bf16x4 o; o[0] = (bf16_t)v.x; o[1] = (bf16_t)v.y; o[2] = (bf16_t)v.z; o[3] = (bf16_t)v.w;
        *(bf16x4*)&audio_bf[ea] = o;
    }
}

// a_w1 [2048][1024] fp32 -> W1topT [1024][1024] bf16, W1botT bf16 (transposed)
__global__ __launch_bounds__(256) void cvt_w1T_k(
    const float* __restrict__ w1, bf16_t* __restrict__ topT, bf16_t* __restrict__ botT)
{
    __shared__ float tile[32][33];
    const int bx = blockIdx.x, by = blockIdx.y;       // (32, 64)
    const int tx = threadIdx.x & 31, ty = threadIdx.x >> 5;
    #pragma unroll
    for (int j = 0; j < 4; ++j)
        tile[ty + j * 8][tx] = w1[(size_t)(by * 32 + ty + j * 8) * 1024 + bx * 32 + tx];
    __syncthreads();
    bf16_t* out = (by < 32) ? topT : botT;
    const int hbase = (by & 31) * 32;
    #pragma unroll
    for (int j = 0; j < 4; ++j) {
        const int d = bx * 32 + ty + j * 8;
        out[(size_t)d * 1024 + hbase + tx] = (bf16_t)tile[tx][ty + j * 8];
    }
}

// d_w [1024][1024*3] fp32 ([o][i][r]) -> Wc [3][1024][1024] bf16 ([r][o][i])
__global__ __launch_bounds__(256) void cvt_wc_k(
    const float* __restrict__ w, bf16_t* __restrict__ wc)
{
    const int t = blockIdx.x * 256 + threadIdx.x;     // 262144 threads
    const int o = t >> 8, i4 = t & 255;
    const float* src = w + (size_t)o * 3072 + i4 * 12;
    float4 v0 = *(const float4*)&src[0];
    float4 v1 = *(const float4*)&src[4];
    float4 v2 = *(const float4*)&src[8];
    const float f[12] = {v0.x, v0.y, v0.z, v0.w, v1.x, v1.y, v1.z, v1.w, v2.x, v2.y, v2.z, v2.w};
    #pragma unroll
    for (int r = 0; r < 3; ++r) {
        bf16x4 o4;
        #pragma unroll
        for (int j = 0; j < 4; ++j) o4[j] = (bf16_t)f[j * 3 + r];
        *(bf16x4*)&wc[(size_t)r * 1048576 + (size_t)o * 1024 + i4 * 4] = o4;
    }
}

// ---------------------------------------------------------------------------
// 32x64 wave-tile MFMA GEMMs (1 wave/block), direct bf16x8 fragment loads.
// A-frag lane l: m = l&15 (+16*frag), k = (l>>4)*8+j.
// C/D lane l reg r: row = (l>>4)*4+r, col = l&15.
// ---------------------------------------------------------------------------

// tp GEMM: text_bf x W1topT, K=1024, bias folded, f32 out (no split-k)
__global__ __launch_bounds__(64) void gemm_tp_k(
    const bf16_t* __restrict__ A, const bf16_t* __restrict__ Bt,
    const float* __restrict__ b1, float* __restrict__ tp)
{
    const int l = threadIdx.x;
    const int n0 = blockIdx.x * 64, m0 = blockIdx.y * 32;
    const int lm = l & 15, lk = (l >> 4) * 8;
    f32x4 acc[2][4];
    #pragma unroll
    for (int mt = 0; mt < 2; ++mt)
        #pragma unroll
        for (int nt = 0; nt < 4; ++nt) acc[mt][nt] = (f32x4)(0.0f);
    const bf16_t* Ap = A + (size_t)(m0 + lm) * 1024 + lk;
    const bf16_t* Bp = Bt + (size_t)(n0 + lm) * 1024 + lk;
    for (int kk = 0; kk < 1024; kk += 32) {
        bf16x8 af[2], bfr[4];
        #pragma unroll
        for (int i = 0; i < 2; ++i) af[i] = *(const bf16x8*)(Ap + (size_t)i * 16384 + kk);
        #pragma unroll
        for (int i = 0; i < 4; ++i) bfr[i] = *(const bf16x8*)(Bp + (size_t)i * 16384 + kk);
        #pragma unroll
        for (int mt = 0; mt < 2; ++mt)
            #pragma unroll
            for (int nt = 0; nt < 4; ++nt)
                acc[mt][nt] = __builtin_amdgcn_mfma_f32_16x16x32_bf16(af[mt], bfr[nt], acc[mt][nt], 0, 0, 0);
    }
    #pragma unroll
    for (int mt = 0; mt < 2; ++mt) {
        const int row = m0 + mt * 16 + (l >> 4) * 4;
        #pragma unroll
        for (int nt = 0; nt < 4; ++nt) {
            const int col = n0 + nt * 16 + lm;
            const float bb = b1[col];
            #pragma unroll
            for (int r = 0; r < 4; ++r)
                tp[(size_t)(row + r) * 1024 + col] = acc[mt][nt][r] + bb;
        }
    }
}

// ap GEMM: audio_bf x W1botT, K=1024; epilogue -> bf16 apT [h][b*512+a]
__global__ __launch_bounds__(64) void gemm_ap_k(
    const bf16_t* __restrict__ A, const bf16_t* __restrict__ Bt,
    bf16_t* __restrict__ apT)
{
    __shared__ bf16_t T[32][72];
    const int l = threadIdx.x;
    const int n0 = blockIdx.x * 64, m0 = blockIdx.y * 32;
    const int lm = l & 15, lk = (l >> 4) * 8;
    f32x4 acc[2][4];
    #pragma unroll
    for (int mt = 0; mt < 2; ++mt)
        #pragma unroll
        for (int nt = 0; nt < 4; ++nt) acc[mt][nt] = (f32x4)(0.0f);
    const bf16_t* Ap = A + (size_t)(m0 + lm) * 1024 + lk;
    const bf16_t* Bp = Bt + (size_t)(n0 + lm) * 1024 + lk;
    for (int kk = 0; kk < 1024; kk += 32) {
        bf16x8 af[2], bfr[4];
        #pragma unroll
        for (int i = 0; i < 2; ++i) af[i] = *(const bf16x8*)(Ap + (size_t)i * 16384 + kk);
        #pragma unroll
        for (int i = 0; i < 4; ++i) bfr[i] = *(const bf16x8*)(Bp + (size_t)i * 16384 + kk);
        #pragma unroll
        for (int mt = 0; mt < 2; ++mt)
            #pragma unroll
            for (int nt = 0; nt < 4; ++nt)
                acc[mt][nt] = __builtin_amdgcn_mfma_f32_16x16x32_bf16(af[mt], bfr[nt], acc[mt][nt], 0, 0, 0);
    }
    #pragma unroll
    for (int mt = 0; mt < 2; ++mt)
        #pragma unroll
        for (int nt = 0; nt < 4; ++nt)
            #pragma unroll
            for (int r = 0; r < 4; ++r)
                T[mt * 16 + (l >> 4) * 4 + r][nt * 16 + lm] = (bf16_t)acc[mt][nt][r];
    __syncthreads();
    // transposed write: apT[(n0+h)*1024 + b*512 + a0 + a]
    const int b = m0 >> 9, a0 = m0 & 511;
    const int al = l & 31, hh = l >> 5;
    bf16_t* dst = apT + b * 512 + a0 + al;
    #pragma unroll
    for (int i = 0; i < 32; ++i) {
        const int h_loc = i * 2 + hh;
        dst[(size_t)(n0 + h_loc) * 1024] = T[al][h_loc];
    }
}

// conv GEMM: Wc [3][1024][1024] x padded activations xp [2][130][1024], z=4 over i.
__global__ __launch_bounds__(64) void gemm_conv_k(
    const bf16_t* __restrict__ Wc, const bf16_t* __restrict__ xp,
    float* __restrict__ parts)
{
    const int l = threadIdx.x;
    const int n0 = blockIdx.x * 64, m0 = blockIdx.y * 32, i0 = blockIdx.z * 256;
    const int lm = l & 15, lk = (l >> 4) * 8;
    const int b = n0 >> 7, tbase = n0 & 127;
    f32x4 acc[2][4];
    #pragma unroll
    for (int mt = 0; mt < 2; ++mt)
        #pragma unroll
        for (int nt = 0; nt < 4; ++nt) acc[mt][nt] = (f32x4)(0.0f);
    const bf16_t* aq = Wc + (size_t)(m0 + lm) * 1024 + i0 + lk;
    const bf16_t* bq = xp + (size_t)(b * 130 + tbase + lm) * 1024 + i0 + lk;
    #pragma unroll
    for (int r = 0; r < 3; ++r) {
        const bf16_t* ar = aq + (size_t)r * 1048576;
        const bf16_t* br = bq + (size_t)r * 1024;
        for (int kk = 0; kk < 256; kk += 32) {
            bf16x8 af[2], bfr[4];
            #pragma unroll
            for (int i = 0; i < 2; ++i) af[i] = *(const bf16x8*)(ar + (size_t)i * 16384 + kk);
            #pragma unroll
            for (int i = 0; i < 4; ++i) bfr[i] = *(const bf16x8*)(br + (size_t)i * 16384 + kk);
            #pragma unroll
            for (int mt = 0; mt < 2; ++mt)
                #pragma unroll
                for (int nt = 0; nt < 4; ++nt)
                    acc[mt][nt] = __builtin_amdgcn_mfma_f32_16x16x32_bf16(af[mt], bfr[nt], acc[mt][nt], 0, 0, 0);
        }
    }
    float* P = parts + (size_t)blockIdx.z * 262144;
    #pragma unroll
    for (int mt = 0; mt < 2; ++mt) {
        const int row = m0 + mt * 16 + (l >> 4) * 4;
        #pragma unroll
        for (int nt = 0; nt < 4; ++nt) {
            const int col = n0 + nt * 16 + lm;
            #pragma unroll
            for (int r = 0; r < 4; ++r)
                P[(size_t)(row + r) * 256 + col] = acc[mt][nt][r];
        }
    }
}

// reduce conv partials (z=4) -> bias+relu -> bf16 transposed [bt][o] + GN stats
__global__ __launch_bounds__(256) void reduce_convT_k(
    const float* __restrict__ parts, const float* __restrict__ bias,
    bf16_t* __restrict__ out, int rowsPerB, int rowOff,
    float* __restrict__ stats)
{
    __shared__ float T[64][65];
    __shared__ float reds[256], redq[256];
    const int tid = threadIdx.x;
    const int bt0 = blockIdx.x * 64, o0 = blockIdx.y * 64;
    const int b = bt0 >> 7;
    const int ro = tid >> 2, cq = tid & 3;
    float s = 0.f, q = 0.f;
    const float bv = bias[o0 + ro];
    #pragma unroll
    for (int j = 0; j < 4; ++j) {
        const int c4 = cq * 4 + j;
        const float4* src = (const float4*)(parts + (size_t)(o0 + ro) * 256 + bt0) + c4;
        float4 v = src[0];
        #pragma unroll
        for (int z = 1; z < 4; ++z) {
            float4 w = src[z * 65536];
            v.x += w.x; v.y += w.y; v.z += w.z; v.w += w.w;
        }
        v.x = fmaxf(v.x + bv, 0.f); v.y = fmaxf(v.y + bv, 0.f);
        v.z = fmaxf(v.z + bv, 0.f); v.w = fmaxf(v.w + bv, 0.f);
        T[ro][c4 * 4 + 0] = v.x; T[ro][c4 * 4 + 1] = v.y;
        T[ro][c4 * 4 + 2] = v.z; T[ro][c4 * 4 + 3] = v.w;
        s += v.x + v.y + v.z + v.w;
        q += v.x * v.x + v.y * v.y + v.z * v.z + v.w * v.w;
    }
    reds[tid] = s; redq[tid] = q;
    __syncthreads();
    {
        const int rb = tid & 63, og = tid >> 6;
        bf16x8 o8a, o8b;
        #pragma unroll
        for (int j = 0; j < 8; ++j) o8a[j] = (bf16_t)T[og * 16 + j][rb];
        #pragma unroll
        for (int j = 0; j < 8; ++j) o8b[j] = (bf16_t)T[og * 16 + 8 + j][rb];
        const int t = (bt0 & 127) + rb;
        bf16_t* dst = out + (size_t)(b * rowsPerB + rowOff + t) * 1024 + o0 + og * 16;
        *(bf16x8*)dst = o8a;
        *(bf16x8*)(dst + 8) = o8b;
    }
    for (int step = 128; step > 0; step >>= 1) {
        if (tid < step) { reds[tid] += reds[tid + step]; redq[tid] += redq[tid + step]; }
        __syncthreads();
    }
    if (tid == 0) {
        atomicAdd(&stats[b * 2], reds[0]);
        atomicAdd(&stats[b * 2 + 1], redq[0]);
    }
}

// GroupNorm apply in-place on bf16 padded buffer (conv1 only)
__global__ __launch_bounds__(256) void gn_apply_k(
    bf16_t* __restrict__ buf, int rowsPerB, int rowOff,
    const float* __restrict__ stats,
    const float* __restrict__ g, const float* __restrict__ bet)
{
    const int idx4 = blockIdx.x * 256 + threadIdx.x;  // 65536 groups of 4
    const int e = idx4 * 4;
    const int bt = e >> 10, o = e & 1023;
    const int b = bt >> 7, t = bt & 127;
    bf16_t* p = buf + (size_t)(b * rowsPerB + rowOff + t) * 1024 + o;
    const float cnt = 131072.f;
    const float mu = stats[b * 2] / cnt;
    const float var = stats[b * 2 + 1] / cnt - mu * mu;
    const float rs = rsqrtf(var + EPSV);
    bf16x4 v = *(bf16x4*)p;
    float4 gv = *(const float4*)&g[o];
    float4 bv = *(const float4*)&bet[o];
    bf16x4 ov;
    ov[0] = (bf16_t)(((float)v[0] - mu) * rs * gv.x + bv.x);
    ov[1] = (bf16_t)(((float)v[1] - mu) * rs * gv.y + bv.y);
    ov[2] = (bf16_t)(((float)v[2] - mu) * rs * gv.z + bv.z);
    ov[3] = (bf16_t)(((float)v[3] - mu) * rs * gv.w + bv.w);
    *(bf16x4*)p = ov;
}

// durations[bt] = softplus( sum_i GN2(y2)[bt][i]*w3[i] + b3 ), GN folded:
// rs*(S1 - mu*S2) + S3 + b3, S1=sum g*w3*y2, S2=sum g*w3, S3=sum beta*w3.
__global__ __launch_bounds__(256) void conv3_k(
    const bf16_t* __restrict__ y2, const float* __restrict__ stats,
    const float* __restrict__ g, const float* __restrict__ bet,
    const float* __restrict__ w3, const float* __restrict__ b3,
    float* __restrict__ out)
{
    const int lane = threadIdx.x & 63, w = threadIdx.x >> 6;
    const int bt = blockIdx.x * 4 + w;
    const int b = bt >> 7;
    const float cnt = 131072.f;
    const float mu = stats[b * 2] / cnt;
    const float var = stats[b * 2 + 1] / cnt - mu * mu;
    const float rs = rsqrtf(var + EPSV);
    const bf16_t* row = y2 + (size_t)bt * 1024 + lane * 16;
    float s1 = 0.f, s2 = 0.f, s3 = 0.f;
    #pragma unroll
    for (int c = 0; c < 2; ++c) {
        bf16x8 yv = *(const bf16x8*)(row + c * 8);
        #pragma unroll
        for (int j = 0; j < 8; ++j) {
            const int i = lane * 16 + c * 8 + j;
            const float gw = g[i] * w3[i];
            s1 += gw * (float)yv[j];
            s2 += gw;
            s3 += bet[i] * w3[i];
        }
    }
    #pragma unroll
    for (int off = 32; off > 0; off >>= 1) {
        s1 += __shfl_xor(s1, off);
        s2 += __shfl_xor(s2, off);
        s3 += __shfl_xor(s3, off);
    }
    if (lane == 0) {
        const float t = rs * (s1 - mu * s2) + s3 + b3[0];
        out[bt] = fmaxf(t, 0.f) + log1pf(expf(-fabsf(t)));
    }
}

// fused logits + softmax: block = one (b,t) row, 512 threads = a lanes.
// logits = sum_h relu(tp[t,h] + apT[h,a]) * w2[h] + b2 - 0.1|a-4t|
__global__ __launch_bounds__(512) void logits_k(
    const float* __restrict__ tp, const bf16_t* __restrict__ apT,
    const float* __restrict__ w2, const float* __restrict__ b2,
    float* __restrict__ out)
{
    __shared__ float redm[8], redsum[8];
    const int bt = blockIdx.x;
    const int b = bt >> 7, t = bt & 127;
    const int a = threadIdx.x;
    const int lane = a & 63, wid = a >> 6;
    const float* tpr = tp + (size_t)bt * 1024;           // wave-uniform
    const unsigned short* apc = (const unsigned short*)apT + b * 512 + a;
    float acc = 0.f;
    for (int h = 0; h < 1024; h += 8) {
        float4 t0 = *(const float4*)&tpr[h];
        float4 t1 = *(const float4*)&tpr[h + 4];
        float4 w0 = *(const float4*)&w2[h];
        float4 w1 = *(const float4*)&w2[h + 4];
        const float tv[8] = {t0.x, t0.y, t0.z, t0.w, t1.x, t1.y, t1.z, t1.w};
        const float wv[8] = {w0.x, w0.y, w0.z, w0.w, w1.x, w1.y, w1.z, w1.w};
        #pragma unroll
        for (int j = 0; j < 8; ++j) {
            const unsigned u = (unsigned)apc[(size_t)(h + j) * 1024] << 16;
            acc += fmaxf(tv[j] + __uint_as_float(u), 0.f) * wv[j];
        }
    }
    const float lg = acc + b2[0] - 0.1f * fabsf((float)a - 4.0f * (float)t);
    // softmax over 512 threads: wave shfl reduce + 8-entry LDS
    float m = lg;
    #pragma unroll
    for (int off = 32; off > 0; off >>= 1) m = fmaxf(m, __shfl_xor(m, off));
    if (lane == 0) redm[wid] = m;
    __syncthreads();
    float M = redm[0];
    #pragma unroll
    for (int i = 1; i < 8; ++i) M = fmaxf(M, redm[i]);
    const float e = expf(lg - M);
    float s = e;
    #pragma unroll
    for (int off = 32; off > 0; off >>= 1) s += __shfl_xor(s, off);
    if (lane == 0) redsum[wid] = s;
    __syncthreads();
    float S = redsum[0];
    #pragma unroll
    for (int i = 1; i < 8; ++i) S += redsum[i];
    out[(size_t)bt * 512 + a] = e * (1.0f / S);
}

extern "C" void kernel_launch(void* const* d_in, const int* in_sizes, int n_in,
                              void* d_out, int out_size, void* d_ws, size_t ws_size,
                              hipStream_t stream) {
    const float* text   = (const float*)d_in[0];
    const float* audio  = (const float*)d_in[1];
    const float* a_w1   = (const float*)d_in[2];
    const float* a_b1   = (const float*)d_in[3];
    const float* a_w2   = (const float*)d_in[4];
    const float* a_b2   = (const float*)d_in[5];
    const float* d_w1   = (const float*)d_in[6];
    const float* d_b1   = (const float*)d_in[7];
    const float* gn1_g  = (const float*)d_in[8];
    const float* gn1_b  = (const float*)d_in[9];
    const float* d_w2   = (const float*)d_in[10];
    const float* d_b2   = (const float*)d_in[11];
    const float* gn2_g  = (const float*)d_in[12];
    const float* gn2_b  = (const float*)d_in[13];
    const float* d_w3   = (const float*)d_in[14];
    const float* d_b3   = (const float*)d_in[15];

    char* ws = (char*)d_ws;
    float* outf = (float*)d_out;

    bf16_t* text_bf  = (bf16_t*)(ws + OFF_TEXTBF);
    bf16_t* audio_bf = (bf16_t*)(ws + OFF_AUDIOBF);
    bf16_t* w1topT   = (bf16_t*)(ws + OFF_W1TOP);
    bf16_t* w1botT   = (bf16_t*)(ws + OFF_W1BOT);
    bf16_t* wc       = (bf16_t*)(ws + OFF_WC);     // overlays stage-1 buffers
    float*  tp       = (float*) (ws + OFF_TP);
    bf16_t* apT      = (bf16_t*)(ws + OFF_APT);
    bf16_t* xp0      = (bf16_t*)(ws + OFF_XP0);
    bf16_t* xp1      = (bf16_t*)(ws + OFF_XP1);
    float*  stats    = (float*) (ws + OFF_STATS);
    bf16_t* y2       = (bf16_t*)(ws + OFF_Y2);
    float*  parts    = (float*) (ws + OFF_PARTS);

    // zero xp0+xp1 pad rows + stats (one contiguous region)
    hipMemsetAsync(ws + OFF_XP0, 0, 532480u + 532480u + 32u, stream);

    // prep
    cvt_act_k<<<dim3(1280), 256, 0, stream>>>(text, audio, text_bf, xp0, audio_bf);
    cvt_w1T_k<<<dim3(32, 64), 256, 0, stream>>>(a_w1, w1topT, w1botT);

    // tp = f32(text @ W1_top + b1), direct epilogue
    gemm_tp_k<<<dim3(16, 8), 64, 0, stream>>>(text_bf, w1topT, a_b1, tp);

    // apT = bf16(audio @ W1_bot)^T  [h][b*512+a]
    gemm_ap_k<<<dim3(16, 32), 64, 0, stream>>>(audio_bf, w1botT, apT);

    // conv1 -> GN1 (wc overlays stage-1 buffers; all consumers already ran)
    cvt_wc_k<<<dim3(1024), 256, 0, stream>>>(d_w1, wc);
    gemm_conv_k<<<dim3(4, 32, 4), 64, 0, stream>>>(wc, xp0, parts);
    reduce_convT_k<<<dim3(4, 16), 256, 0, stream>>>(parts, d_b1, xp1, 130, 1, stats);
    gn_apply_k<<<dim3(256), 256, 0, stream>>>(xp1, 130, 1, stats, gn1_g, gn1_b);

    // conv2 -> y2 (pre-GN; GN2 folded into conv3)
    cvt_wc_k<<<dim3(1024), 256, 0, stream>>>(d_w2, wc);
    gemm_conv_k<<<dim3(4, 32, 4), 64, 0, stream>>>(wc, xp1, parts);
    reduce_convT_k<<<dim3(4, 16), 256, 0, stream>>>(parts, d_b2, y2, 128, 0, stats + 4);

    // conv3 + GN2-fold + softplus -> durations
    conv3_k<<<dim3(64), 256, 0, stream>>>(y2, stats + 4, gn2_g, gn2_b, d_w3, d_b3,
                                          outf + 131072);

    // fused logits + softmax -> alignment
    logits_k<<<dim3(256), 512, 0, stream>>>(tp, apT, a_w2, a_b2, outf);
}

// Round 5
// 240.534 us; speedup vs baseline: 1.0414x; 1.0414x over previous
//
#include <hip/hip_runtime.h>
#include <hip/hip_bf16.h>

// ---------------------------------------------------------------------------
// MonotonicAlignmentSearch R5: h-split high-occupancy logits with quad-packed
// apT (8B loads = 4 h), fused conv gemm+reduce (in-LDS split-k), 8 dispatches.
// B=2, TT=128, TA=512, H=1024.
// ---------------------------------------------------------------------------

typedef __bf16 bf16_t;
typedef __bf16 bf16x8 __attribute__((ext_vector_type(8)));
typedef __bf16 bf16x4 __attribute__((ext_vector_type(4)));
typedef float  f32x4  __attribute__((ext_vector_type(4)));

#define EPSV 1e-5f

// ---- workspace offsets (bytes), total 17842208 (== proven-good size) ------
#define OFF_TEXTBF   0u          //  524288  bf16 text [256][1024]      (stage1)
#define OFF_AUDIOBF  524288u     // 2097152  bf16 audio [1024][1024]    (stage1)
#define OFF_W1TOP    2621440u    // 2097152  bf16 W1topT [1024][1024]   (stage1)
#define OFF_W1BOT    4718592u    // 2097152  bf16 W1botT [1024][1024]   (stage1)
#define OFF_WC1      0u          // 6291456  bf16 Wc1 (overlays stage1 after gemms)
#define OFF_WC2      6815744u    // 6291456  bf16 Wc2
#define OFF_TP       13107200u   // 1048576  f32 tp [256][1024] (bias folded)
#define OFF_APT      14155776u   // 2097152  bf16 apT4 [256 hq][1024 ba][4]
#define OFF_XP0      16252928u   //  532480  bf16 xp0 [2][130][1024]
#define OFF_XP1      16785408u   //  532480  bf16 xp1 [2][130][1024]
#define OFF_Y2       17317888u   //  524288  bf16 y2 [256][1024] (pre-GN2)
#define OFF_STATS    17842176u   //      32  8 f32 GN stats
#define OFF_LP       0u          // 2097152  f32 lp [4 hc][256 bt][512 a]
                                 //          (overlays Wc1; Wc1 dead after conv1)

// ---------------------------------------------------------------------------
// prep: cvt text/audio to bf16 (+ padded xp0), transpose-cast w1, zero pads
// blocks [0,1280): activations; [1280,3328): w1 transpose; 3328: zero pads+stats
// ---------------------------------------------------------------------------
__global__ __launch_bounds__(256) void prep_k(
    const float* __restrict__ text, const float* __restrict__ audio,
    const float* __restrict__ w1,
    bf16_t* __restrict__ text_bf, bf16_t* __restrict__ xp0,
    bf16_t* __restrict__ audio_bf,
    bf16_t* __restrict__ topT, bf16_t* __restrict__ botT,
    bf16_t* __restrict__ xp1, float* __restrict__ stats)
{
    __shared__ float tile[32][33];
    const int bid = blockIdx.x;
    if (bid < 1280) {
        const int e = (bid * 256 + threadIdx.x) * 4;   // 1310720 total
        if (e < 262144) {
            float4 v = *(const float4*)&text[e];
            bf16x4 o; o[0] = (bf16_t)v.x; o[1] = (bf16_t)v.y; o[2] = (bf16_t)v.z; o[3] = (bf16_t)v.w;
            *(bf16x4*)&text_bf[e] = o;
            const int bt = e >> 10, h = e & 1023;
            const int b = bt >> 7, t = bt & 127;
            *(bf16x4*)&xp0[(size_t)(b * 130 + 1 + t) * 1024 + h] = o;
        } else {
            const int ea = e - 262144;
            float4 v = *(const float4*)&audio[ea];
            bf16x4 o; o[0] = (bf16_t)v.x; o[1] = (bf16_t)v.y; o[2] = (bf16_t)v.z; o[3] = (bf16_t)v.w;
            *(bf16x4*)&audio_bf[ea] = o;
        }
    } else if (bid < 3328) {
        const int b2 = bid - 1280;
        const int bx = b2 & 31, by = b2 >> 5;          // (32, 64)
        const int tx = threadIdx.x & 31, ty = threadIdx.x >> 5;
        #pragma unroll
        for (int j = 0; j < 4; ++j)
            tile[ty + j * 8][tx] = w1[(size_t)(by * 32 + ty + j * 8) * 1024 + bx * 32 + tx];
        __syncthreads();
        bf16_t* out = (by < 32) ? topT : botT;
        const int hbase = (by & 31) * 32;
        #pragma unroll
        for (int j = 0; j < 4; ++j) {
            const int d = bx * 32 + ty + j * 8;
            out[(size_t)d * 1024 + hbase + tx] = (bf16_t)tile[tx][ty + j * 8];
        }
    } else {
        // zero pad rows of xp0/xp1 (rows 0,129 per b) + stats
        const int tid = threadIdx.x;
        const int rowmap[4] = {0, 129, 130, 259};
        const int f = tid * 16;                        // 4096 elems per buffer
        const int r = f >> 10, w = f & 1023;
        bf16x8 z8 = (bf16x8)(bf16_t)0.0f;
        bf16_t* p0 = xp0 + (size_t)rowmap[r] * 1024 + w;
        bf16_t* p1 = xp1 + (size_t)rowmap[r] * 1024 + w;
        *(bf16x8*)p0 = z8; *(bf16x8*)(p0 + 8) = z8;
        *(bf16x8*)p1 = z8; *(bf16x8*)(p1 + 8) = z8;
        if (tid < 8) stats[tid] = 0.0f;
    }
}

// d_w1/d_w2 [1024][1024*3] fp32 ([o][i][r]) -> Wc [3][1024][1024] bf16 ([r][o][i])
__global__ __launch_bounds__(256) void cvt_wc_k(
    const float* __restrict__ w1c, const float* __restrict__ w2c,
    bf16_t* __restrict__ wc1, bf16_t* __restrict__ wc2)
{
    int bid = blockIdx.x;
    const float* w = (bid < 1024) ? w1c : w2c;
    bf16_t* wc = (bid < 1024) ? wc1 : wc2;
    bid &= 1023;
    const int t = bid * 256 + threadIdx.x;
    const int o = t >> 8, i4 = t & 255;
    const float* src = w + (size_t)o * 3072 + i4 * 12;
    float4 v0 = *(const float4*)&src[0];
    float4 v1 = *(const float4*)&src[4];
    float4 v2 = *(const float4*)&src[8];
    const float f[12] = {v0.x, v0.y, v0.z, v0.w, v1.x, v1.y, v1.z, v1.w, v2.x, v2.y, v2.z, v2.w};
    #pragma unroll
    for (int r = 0; r < 3; ++r) {
        bf16x4 o4;
        #pragma unroll
        for (int j = 0; j < 4; ++j) o4[j] = (bf16_t)f[j * 3 + r];
        *(bf16x4*)&wc[(size_t)r * 1048576 + (size_t)o * 1024 + i4 * 4] = o4;
    }
}

// ---------------------------------------------------------------------------
// merged tp+ap GEMM (1-wave 32x64 tiles, direct bf16x8 fragment loads).
// blocks [0,128): tp = f32(text@W1top + b1).  [128,640): apT4 quad-packed.
// A-frag lane l: m=l&15 (+16*frag), k=(l>>4)*8+j. C/D: row=(l>>4)*4+r, col=l&15.
// ---------------------------------------------------------------------------
__global__ __launch_bounds__(64) void gemm_tpap_k(
    const bf16_t* __restrict__ text_bf, const bf16_t* __restrict__ w1topT,
    const float* __restrict__ b1, float* __restrict__ tp,
    const bf16_t* __restrict__ audio_bf, const bf16_t* __restrict__ w1botT,
    bf16_t* __restrict__ apT4)
{
    __shared__ bf16_t T[32][68];
    const int bid = blockIdx.x;
    const int is_tp = (bid < 128) ? 1 : 0;
    const int b2 = is_tp ? bid : bid - 128;
    const int n0 = (b2 & 15) * 64, m0 = (b2 >> 4) * 32;
    const int l = threadIdx.x;
    const int lm = l & 15, lk = (l >> 4) * 8;
    const bf16_t* A  = is_tp ? text_bf : audio_bf;
    const bf16_t* Bt = is_tp ? w1topT : w1botT;
    f32x4 acc[2][4];
    #pragma unroll
    for (int mt = 0; mt < 2; ++mt)
        #pragma unroll
        for (int nt = 0; nt < 4; ++nt) acc[mt][nt] = (f32x4)(0.0f);
    const bf16_t* Ap = A + (size_t)(m0 + lm) * 1024 + lk;
    const bf16_t* Bp = Bt + (size_t)(n0 + lm) * 1024 + lk;
    for (int kk = 0; kk < 1024; kk += 32) {
        bf16x8 af[2], bfr[4];
        #pragma unroll
        for (int i = 0; i < 2; ++i) af[i] = *(const bf16x8*)(Ap + (size_t)i * 16384 + kk);
        #pragma unroll
        for (int i = 0; i < 4; ++i) bfr[i] = *(const bf16x8*)(Bp + (size_t)i * 16384 + kk);
        #pragma unroll
        for (int mt = 0; mt < 2; ++mt)
            #pragma unroll
            for (int nt = 0; nt < 4; ++nt)
                acc[mt][nt] = __builtin_amdgcn_mfma_f32_16x16x32_bf16(af[mt], bfr[nt], acc[mt][nt], 0, 0, 0);
    }
    if (is_tp) {
        #pragma unroll
        for (int mt = 0; mt < 2; ++mt) {
            const int row = m0 + mt * 16 + (l >> 4) * 4;
            #pragma unroll
            for (int nt = 0; nt < 4; ++nt) {
                const int col = n0 + nt * 16 + lm;
                const float bb = b1[col];
                #pragma unroll
                for (int r = 0; r < 4; ++r)
                    tp[(size_t)(row + r) * 1024 + col] = acc[mt][nt][r] + bb;
            }
        }
    } else {
        // T[a-local][h-local]
        #pragma unroll
        for (int mt = 0; mt < 2; ++mt)
            #pragma unroll
            for (int nt = 0; nt < 4; ++nt)
                #pragma unroll
                for (int r = 0; r < 4; ++r)
                    T[mt * 16 + (l >> 4) * 4 + r][nt * 16 + lm] = (bf16_t)acc[mt][nt][r];
        __syncthreads();
        // quad-packed write: apT4[(hq*1024 + b*512 + a)*4 + c], hq = (n0+q*4)/4
        const int b = m0 >> 9, a0 = m0 & 511;
        const int al = l & 31, qh = l >> 5;
        #pragma unroll
        for (int i = 0; i < 8; ++i) {
            const int q = i * 2 + qh;                  // 16 quads cover 64 h
            bf16x4 v;
            #pragma unroll
            for (int c = 0; c < 4; ++c) v[c] = T[al][q * 4 + c];
            const size_t hq = (size_t)(n0 >> 2) + q;
            *(bf16x4*)&apT4[(hq * 1024 + b * 512 + a0 + al) * 4] = v;
        }
    }
}

// ---------------------------------------------------------------------------
// fused conv gemm + split-k in-LDS reduce + bias/relu + GN stats + bf16
// transposed write. Tile 16m x 64n, 4 waves = 4 i-chunks of 256. Grid (4,64).
// ---------------------------------------------------------------------------
__global__ __launch_bounds__(256) void conv_fused_k(
    const bf16_t* __restrict__ Wc, const bf16_t* __restrict__ xp,
    const float* __restrict__ bias, bf16_t* __restrict__ out,
    int rowsPerB, int rowOff, float* __restrict__ stats)
{
    __shared__ float red[4][16][66];
    const int tid = threadIdx.x;
    const int w = tid >> 6, l = tid & 63;
    const int n0 = blockIdx.x * 64, m0 = blockIdx.y * 16;
    const int i0 = w * 256;
    const int lm = l & 15, lk = (l >> 4) * 8;
    const int b = n0 >> 7, tbase = n0 & 127;
    f32x4 acc[4];
    #pragma unroll
    for (int nt = 0; nt < 4; ++nt) acc[nt] = (f32x4)(0.0f);
    const bf16_t* aq = Wc + (size_t)(m0 + lm) * 1024 + i0 + lk;
    const bf16_t* bq = xp + (size_t)(b * 130 + tbase + lm) * 1024 + i0 + lk;
    #pragma unroll
    for (int r = 0; r < 3; ++r) {
        const bf16_t* ar = aq + (size_t)r * 1048576;
        const bf16_t* br = bq + (size_t)r * 1024;
        for (int kk = 0; kk < 256; kk += 32) {
            bf16x8 af = *(const bf16x8*)(ar + kk);
            bf16x8 bfr[4];
            #pragma unroll
            for (int i = 0; i < 4; ++i) bfr[i] = *(const bf16x8*)(br + (size_t)i * 16384 + kk);
            #pragma unroll
            for (int nt = 0; nt < 4; ++nt)
                acc[nt] = __builtin_amdgcn_mfma_f32_16x16x32_bf16(af, bfr[nt], acc[nt], 0, 0, 0);
        }
    }
    // stash per-wave partials
    #pragma unroll
    for (int nt = 0; nt < 4; ++nt) {
        const int row = (l >> 4) * 4;
        #pragma unroll
        for (int r = 0; r < 4; ++r)
            red[w][row + r][nt * 16 + lm] = acc[nt][r];
    }
    __syncthreads();
    // reduce across waves; cells tid, tid+256, tid+512, tid+768
    float s = 0.f, q = 0.f;
    float vv[4];
    #pragma unroll
    for (int k = 0; k < 4; ++k) {
        const int cell = tid + k * 256;
        const int m = cell >> 6, n = cell & 63;
        float v = red[0][m][n] + red[1][m][n] + red[2][m][n] + red[3][m][n];
        v = fmaxf(v + bias[m0 + m], 0.f);
        vv[k] = v;
        s += v; q += v * v;
    }
    __syncthreads();
    #pragma unroll
    for (int k = 0; k < 4; ++k) {
        const int cell = tid + k * 256;
        red[0][cell >> 6][cell & 63] = vv[k];
    }
    // GN stats: wave reduce then one atomic per wave
    #pragma unroll
    for (int off = 32; off > 0; off >>= 1) {
        s += __shfl_xor(s, off);
        q += __shfl_xor(q, off);
    }
    if (l == 0) {
        atomicAdd(&stats[b * 2], s);
        atomicAdd(&stats[b * 2 + 1], q);
    }
    __syncthreads();
    // transposed write: out[bt][o], 128 threads, 8 o's each
    if (tid < 128) {
        const int n = tid >> 1, half = tid & 1;
        bf16x8 o8;
        #pragma unroll
        for (int j = 0; j < 8; ++j) o8[j] = (bf16_t)red[0][half * 8 + j][n];
        const int t = tbase + n;
        *(bf16x8*)&out[(size_t)(b * rowsPerB + rowOff + t) * 1024 + m0 + half * 8] = o8;
    }
}

// GroupNorm apply in-place on padded bf16 buffer (conv1 only)
__global__ __launch_bounds__(256) void gn_apply_k(
    bf16_t* __restrict__ buf, const float* __restrict__ stats,
    const float* __restrict__ g, const float* __restrict__ bet)
{
    const int idx4 = blockIdx.x * 256 + threadIdx.x;  // 65536 groups of 4
    const int e = idx4 * 4;
    const int bt = e >> 10, o = e & 1023;
    const int b = bt >> 7, t = bt & 127;
    bf16_t* p = buf + (size_t)(b * 130 + 1 + t) * 1024 + o;
    const float cnt = 131072.f;
    const float mu = stats[b * 2] / cnt;
    const float var = stats[b * 2 + 1] / cnt - mu * mu;
    const float rs = rsqrtf(var + EPSV);
    bf16x4 v = *(bf16x4*)p;
    float4 gv = *(const float4*)&g[o];
    float4 bv = *(const float4*)&bet[o];
    bf16x4 ov;
    ov[0] = (bf16_t)(((float)v[0] - mu) * rs * gv.x + bv.x);
    ov[1] = (bf16_t)(((float)v[1] - mu) * rs * gv.y + bv.y);
    ov[2] = (bf16_t)(((float)v[2] - mu) * rs * gv.z + bv.z);
    ov[3] = (bf16_t)(((float)v[3] - mu) * rs * gv.w + bv.w);
    *(bf16x4*)p = ov;
}

// ---------------------------------------------------------------------------
// logits partials: lp[hc][bt][a] = sum_{h in chunk} relu(tp[bt,h]+ap[h,a])*w2[h]
// grid (256 bt, 4 hc) x 512 threads (a). apT4 quad-packed: one 8B load = 4 h.
// ---------------------------------------------------------------------------
__global__ __launch_bounds__(512) void logits_k(
    const float* __restrict__ tp, const bf16_t* __restrict__ apT4,
    const float* __restrict__ w2, float* __restrict__ lp)
{
    const int bt = blockIdx.x, hc = blockIdx.y;
    const int b = bt >> 7;
    const int a = threadIdx.x;
    const float* tpr = tp + (size_t)bt * 1024 + hc * 256;   // wave-uniform
    const float* w2r = w2 + hc * 256;
    const bf16_t* apc = apT4 + ((size_t)(hc * 64) * 1024 + b * 512 + a) * 4;
    float acc = 0.f;
    #pragma unroll 4
    for (int hq = 0; hq < 64; hq += 2) {                    // 8 h per iter
        bf16x4 a0 = *(const bf16x4*)(apc + (size_t)hq * 4096);
        bf16x4 a1 = *(const bf16x4*)(apc + (size_t)(hq + 1) * 4096);
        float4 t0 = *(const float4*)&tpr[hq * 4];
        float4 t1 = *(const float4*)&tpr[hq * 4 + 4];
        float4 w0 = *(const float4*)&w2r[hq * 4];
        float4 w1 = *(const float4*)&w2r[hq * 4 + 4];
        acc += fmaxf(t0.x + (float)a0[0], 0.f) * w0.x;
        acc += fmaxf(t0.y + (float)a0[1], 0.f) * w0.y;
        acc += fmaxf(t0.z + (float)a0[2], 0.f) * w0.z;
        acc += fmaxf(t0.w + (float)a0[3], 0.f) * w0.w;
        acc += fmaxf(t1.x + (float)a1[0], 0.f) * w1.x;
        acc += fmaxf(t1.y + (float)a1[1], 0.f) * w1.y;
        acc += fmaxf(t1.z + (float)a1[2], 0.f) * w1.z;
        acc += fmaxf(t1.w + (float)a1[3], 0.f) * w1.w;
    }
    lp[(size_t)(hc * 256 + bt) * 512 + a] = acc;
}

// ---------------------------------------------------------------------------
// combine: blocks [0,256): sum lp chunks + bias + monotonic, softmax -> out.
//          blocks [256,288): conv3 + GN2-fold + softplus -> durations.
// ---------------------------------------------------------------------------
__global__ __launch_bounds__(512) void combine_k(
    const float* __restrict__ lp, const float* __restrict__ b2,
    const bf16_t* __restrict__ y2, const float* __restrict__ stats2,
    const float* __restrict__ g, const float* __restrict__ bet,
    const float* __restrict__ w3, const float* __restrict__ b3,
    float* __restrict__ out)
{
    __shared__ float redm[8], redsum[8];
    const int bid = blockIdx.x;
    const int tid = threadIdx.x;
    if (bid < 256) {
        const int bt = bid, t = bt & 127;
        const int a = tid;
        const int lane = a & 63, wid = a >> 6;
        const size_t base = (size_t)bt * 512 + a;
        float v = lp[base] + lp[131072 + base] + lp[262144 + base] + lp[393216 + base];
        v += b2[0] - 0.1f * fabsf((float)a - 4.0f * (float)t);
        float m = v;
        #pragma unroll
        for (int off = 32; off > 0; off >>= 1) m = fmaxf(m, __shfl_xor(m, off));
        if (lane == 0) redm[wid] = m;
        __syncthreads();
        float M = redm[0];
        #pragma unroll
        for (int i = 1; i < 8; ++i) M = fmaxf(M, redm[i]);
        const float e = expf(v - M);
        float s = e;
        #pragma unroll
        for (int off = 32; off > 0; off >>= 1) s += __shfl_xor(s, off);
        if (lane == 0) redsum[wid] = s;
        __syncthreads();
        float S = redsum[0];
        #pragma unroll
        for (int i = 1; i < 8; ++i) S += redsum[i];
        out[(size_t)bt * 512 + a] = e * (1.0f / S);
    } else {
        const int lane = tid & 63, w = tid >> 6;
        const int bt = (bid - 256) * 8 + w;
        const int b = bt >> 7;
        const float cnt = 131072.f;
        const float mu = stats2[b * 2] / cnt;
        const float var = stats2[b * 2 + 1] / cnt - mu * mu;
        const float rs = rsqrtf(var + EPSV);
        const bf16_t* row = y2 + (size_t)bt * 1024 + lane * 16;
        float s1 = 0.f, s2 = 0.f, s3 = 0.f;
        #pragma unroll
        for (int c = 0; c < 2; ++c) {
            bf16x8 yv = *(const bf16x8*)(row + c * 8);
            #pragma unroll
            for (int j = 0; j < 8; ++j) {
                const int i = lane * 16 + c * 8 + j;
                const float gw = g[i] * w3[i];
                s1 += gw * (float)yv[j];
                s2 += gw;
                s3 += bet[i] * w3[i];
            }
        }
        #pragma unroll
        for (int off = 32; off > 0; off >>= 1) {
            s1 += __shfl_xor(s1, off);
            s2 += __shfl_xor(s2, off);
            s3 += __shfl_xor(s3, off);
        }
        if (lane == 0) {
            const float t = rs * (s1 - mu * s2) + s3 + b3[0];
            out[131072 + bt] = fmaxf(t, 0.f) + log1pf(expf(-fabsf(t)));
        }
    }
}

extern "C" void kernel_launch(void* const* d_in, const int* in_sizes, int n_in,
                              void* d_out, int out_size, void* d_ws, size_t ws_size,
                              hipStream_t stream) {
    const float* text   = (const float*)d_in[0];
    const float* audio  = (const float*)d_in[1];
    const float* a_w1   = (const float*)d_in[2];
    const float* a_b1   = (const float*)d_in[3];
    const float* a_w2   = (const float*)d_in[4];
    const float* a_b2   = (const float*)d_in[5];
    const float* d_w1   = (const float*)d_in[6];
    const float* d_b1   = (const float*)d_in[7];
    const float* gn1_g  = (const float*)d_in[8];
    const float* gn1_b  = (const float*)d_in[9];
    const float* d_w2   = (const float*)d_in[10];
    const float* d_b2   = (const float*)d_in[11];
    const float* gn2_g  = (const float*)d_in[12];
    const float* gn2_b  = (const float*)d_in[13];
    const float* d_w3   = (const float*)d_in[14];
    const float* d_b3   = (const float*)d_in[15];

    char* ws = (char*)d_ws;
    float* outf = (float*)d_out;

    bf16_t* text_bf  = (bf16_t*)(ws + OFF_TEXTBF);
    bf16_t* audio_bf = (bf16_t*)(ws + OFF_AUDIOBF);
    bf16_t* w1topT   = (bf16_t*)(ws + OFF_W1TOP);
    bf16_t* w1botT   = (bf16_t*)(ws + OFF_W1BOT);
    bf16_t* wc1      = (bf16_t*)(ws + OFF_WC1);   // overlays stage1 after gemms
    bf16_t* wc2      = (bf16_t*)(ws + OFF_WC2);
    float*  tp       = (float*) (ws + OFF_TP);
    bf16_t* apT4     = (bf16_t*)(ws + OFF_APT);
    bf16_t* xp0      = (bf16_t*)(ws + OFF_XP0);
    bf16_t* xp1      = (bf16_t*)(ws + OFF_XP1);
    bf16_t* y2       = (bf16_t*)(ws + OFF_Y2);
    float*  stats    = (float*) (ws + OFF_STATS);
    float*  lp       = (float*) (ws + OFF_LP);    // overlays Wc1 after conv1

    // 1: cvt activations + w1 transpose + zero pads/stats
    prep_k<<<dim3(3329), 256, 0, stream>>>(text, audio, a_w1, text_bf, xp0,
                                           audio_bf, w1topT, w1botT, xp1, stats);
    // 2: tp (f32, bias folded) + apT4 (bf16 quad-packed) GEMMs
    gemm_tpap_k<<<dim3(640), 64, 0, stream>>>(text_bf, w1topT, a_b1, tp,
                                              audio_bf, w1botT, apT4);
    // 3: conv weights (both) -> Wc1/Wc2  (Wc1 overlays dead stage-1 buffers)
    cvt_wc_k<<<dim3(2048), 256, 0, stream>>>(d_w1, d_w2, wc1, wc2);
    // 4: conv1 fused (gemm + reduce + bias/relu + stats + transposed write)
    conv_fused_k<<<dim3(4, 64), 256, 0, stream>>>(wc1, xp0, d_b1, xp1, 130, 1, stats);
    // 5: GN1 apply
    gn_apply_k<<<dim3(256), 256, 0, stream>>>(xp1, stats, gn1_g, gn1_b);
    // 6: conv2 fused -> y2 (pre-GN2)
    conv_fused_k<<<dim3(4, 64), 256, 0, stream>>>(wc2, xp1, d_b2, y2, 128, 0, stats + 4);
    // 7: logits partials (h-split x4; lp overlays dead Wc1)
    logits_k<<<dim3(256, 4), 512, 0, stream>>>(tp, apT4, a_w2, lp);
    // 8: combine+softmax -> alignment; conv3+GN2fold+softplus -> durations
    combine_k<<<dim3(288), 512, 0, stream>>>(lp, a_b2, y2, stats + 4,
                                             gn2_g, gn2_b, d_w3, d_b3, outf);
}

// Round 6
// 208.896 us; speedup vs baseline: 1.1991x; 1.1515x over previous
//
#include <hip/hip_runtime.h>
#include <hip/hip_bf16.h>

// ---------------------------------------------------------------------------
// MonotonicAlignmentSearch R6: occupancy-first MFMA kernels.
// conv: 8-wave blocks, in-LDS split-k (4 waves/SIMD). tp/ap: 32x32 wave tiles,
// 4-wave blocks, in-LDS split-k (5 waves/SIMD). B=2, TT=128, TA=512, H=1024.
// ---------------------------------------------------------------------------

typedef __bf16 bf16_t;
typedef __bf16 bf16x8 __attribute__((ext_vector_type(8)));
typedef __bf16 bf16x4 __attribute__((ext_vector_type(4)));
typedef float  f32x4  __attribute__((ext_vector_type(4)));

#define EPSV 1e-5f

// ---- workspace offsets (bytes), total 17842208 (== proven-good size) ------
#define OFF_TEXTBF   0u          //  524288  bf16 text [256][1024]      (stage1)
#define OFF_AUDIOBF  524288u     // 2097152  bf16 audio [1024][1024]    (stage1)
#define OFF_W1TOP    2621440u    // 2097152  bf16 W1topT [1024][1024]   (stage1)
#define OFF_W1BOT    4718592u    // 2097152  bf16 W1botT [1024][1024]   (stage1)
#define OFF_WC1      0u          // 6291456  bf16 Wc1 (overlays stage1 after gemms)
#define OFF_WC2      6815744u    // 6291456  bf16 Wc2
#define OFF_TP       13107200u   // 1048576  f32 tp [256][1024] (bias folded)
#define OFF_APT      14155776u   // 2097152  bf16 apT4 [256 hq][1024 ba][4]
#define OFF_XP0      16252928u   //  532480  bf16 xp0 [2][130][1024]
#define OFF_XP1      16785408u   //  532480  bf16 xp1 [2][130][1024]
#define OFF_Y2       17317888u   //  524288  bf16 y2 [256][1024] (pre-GN2)
#define OFF_STATS    17842176u   //      32  8 f32 GN stats
#define OFF_LP       0u          // 2097152  f32 lp [4 hc][256 bt][512 a]
                                 //          (overlays Wc1; Wc1 dead after conv1)

// ---------------------------------------------------------------------------
// prep: cvt text/audio to bf16 (+ padded xp0), transpose-cast w1, zero pads
// ---------------------------------------------------------------------------
__global__ __launch_bounds__(256) void prep_k(
    const float* __restrict__ text, const float* __restrict__ audio,
    const float* __restrict__ w1,
    bf16_t* __restrict__ text_bf, bf16_t* __restrict__ xp0,
    bf16_t* __restrict__ audio_bf,
    bf16_t* __restrict__ topT, bf16_t* __restrict__ botT,
    bf16_t* __restrict__ xp1, float* __restrict__ stats)
{
    __shared__ float tile[32][33];
    const int bid = blockIdx.x;
    if (bid < 1280) {
        const int e = (bid * 256 + threadIdx.x) * 4;   // 1310720 total
        if (e < 262144) {
            float4 v = *(const float4*)&text[e];
            bf16x4 o; o[0] = (bf16_t)v.x; o[1] = (bf16_t)v.y; o[2] = (bf16_t)v.z; o[3] = (bf16_t)v.w;
            *(bf16x4*)&text_bf[e] = o;
            const int bt = e >> 10, h = e & 1023;
            const int b = bt >> 7, t = bt & 127;
            *(bf16x4*)&xp0[(size_t)(b * 130 + 1 + t) * 1024 + h] = o;
        } else {
            const int ea = e - 262144;
            float4 v = *(const float4*)&audio[ea];
            bf16x4 o; o[0] = (bf16_t)v.x; o[1] = (bf16_t)v.y; o[2] = (bf16_t)v.z; o[3] = (bf16_t)v.w;
            *(bf16x4*)&audio_bf[ea] = o;
        }
    } else if (bid < 3328) {
        const int b2 = bid - 1280;
        const int bx = b2 & 31, by = b2 >> 5;          // (32, 64)
        const int tx = threadIdx.x & 31, ty = threadIdx.x >> 5;
        #pragma unroll
        for (int j = 0; j < 4; ++j)
            tile[ty + j * 8][tx] = w1[(size_t)(by * 32 + ty + j * 8) * 1024 + bx * 32 + tx];
        __syncthreads();
        bf16_t* out = (by < 32) ? topT : botT;
        const int hbase = (by & 31) * 32;
        #pragma unroll
        for (int j = 0; j < 4; ++j) {
            const int d = bx * 32 + ty + j * 8;
            out[(size_t)d * 1024 + hbase + tx] = (bf16_t)tile[tx][ty + j * 8];
        }
    } else {
        const int tid = threadIdx.x;
        const int rowmap[4] = {0, 129, 130, 259};
        const int f = tid * 16;
        const int r = f >> 10, w = f & 1023;
        bf16x8 z8 = (bf16x8)(bf16_t)0.0f;
        bf16_t* p0 = xp0 + (size_t)rowmap[r] * 1024 + w;
        bf16_t* p1 = xp1 + (size_t)rowmap[r] * 1024 + w;
        *(bf16x8*)p0 = z8; *(bf16x8*)(p0 + 8) = z8;
        *(bf16x8*)p1 = z8; *(bf16x8*)(p1 + 8) = z8;
        if (tid < 8) stats[tid] = 0.0f;
    }
}

// d_w1/d_w2 [1024][1024*3] fp32 ([o][i][r]) -> Wc [3][1024][1024] bf16 ([r][o][i])
__global__ __launch_bounds__(256) void cvt_wc_k(
    const float* __restrict__ w1c, const float* __restrict__ w2c,
    bf16_t* __restrict__ wc1, bf16_t* __restrict__ wc2)
{
    int bid = blockIdx.x;
    const float* w = (bid < 1024) ? w1c : w2c;
    bf16_t* wc = (bid < 1024) ? wc1 : wc2;
    bid &= 1023;
    const int t = bid * 256 + threadIdx.x;
    const int o = t >> 8, i4 = t & 255;
    const float* src = w + (size_t)o * 3072 + i4 * 12;
    float4 v0 = *(const float4*)&src[0];
    float4 v1 = *(const float4*)&src[4];
    float4 v2 = *(const float4*)&src[8];
    const float f[12] = {v0.x, v0.y, v0.z, v0.w, v1.x, v1.y, v1.z, v1.w, v2.x, v2.y, v2.z, v2.w};
    #pragma unroll
    for (int r = 0; r < 3; ++r) {
        bf16x4 o4;
        #pragma unroll
        for (int j = 0; j < 4; ++j) o4[j] = (bf16_t)f[j * 3 + r];
        *(bf16x4*)&wc[(size_t)r * 1048576 + (size_t)o * 1024 + i4 * 4] = o4;
    }
}

// ---------------------------------------------------------------------------
// tp+ap GEMM: 32x32 wave tiles, 4 waves/block = k-chunks of 256, LDS reduce.
// blocks [0,256): tp = f32(text@W1top + b1).  [256,1280): apT4 quad-packed.
// A-frag lane l: m=l&15 (+16*frag), k=(l>>4)*8+j. C/D: row=(l>>4)*4+r, col=l&15.
// ---------------------------------------------------------------------------
__global__ __launch_bounds__(256, 4) void gemm_tpap_k(
    const bf16_t* __restrict__ text_bf, const bf16_t* __restrict__ w1topT,
    const float* __restrict__ b1, float* __restrict__ tp,
    const bf16_t* __restrict__ audio_bf, const bf16_t* __restrict__ w1botT,
    bf16_t* __restrict__ apT4)
{
    __shared__ float red[4][32][36];
    const int bid = blockIdx.x;
    const int is_tp = (bid < 256) ? 1 : 0;
    const int b2 = is_tp ? bid : bid - 256;
    const int n0 = (b2 & 31) * 32, m0 = (b2 >> 5) * 32;
    const int tid = threadIdx.x;
    const int w = tid >> 6, l = tid & 63;
    const int lm = l & 15, lk = (l >> 4) * 8;
    const int k0 = w * 256;
    const bf16_t* A  = is_tp ? text_bf : audio_bf;
    const bf16_t* Bt = is_tp ? w1topT : w1botT;
    f32x4 acc[2][2];
    #pragma unroll
    for (int mt = 0; mt < 2; ++mt)
        #pragma unroll
        for (int nt = 0; nt < 2; ++nt) acc[mt][nt] = (f32x4)(0.0f);
    const bf16_t* Ap = A + (size_t)(m0 + lm) * 1024 + k0 + lk;
    const bf16_t* Bp = Bt + (size_t)(n0 + lm) * 1024 + k0 + lk;
    #pragma unroll
    for (int kk = 0; kk < 256; kk += 32) {
        bf16x8 af[2], bfr[2];
        #pragma unroll
        for (int i = 0; i < 2; ++i) af[i] = *(const bf16x8*)(Ap + (size_t)i * 16384 + kk);
        #pragma unroll
        for (int i = 0; i < 2; ++i) bfr[i] = *(const bf16x8*)(Bp + (size_t)i * 16384 + kk);
        #pragma unroll
        for (int mt = 0; mt < 2; ++mt)
            #pragma unroll
            for (int nt = 0; nt < 2; ++nt)
                acc[mt][nt] = __builtin_amdgcn_mfma_f32_16x16x32_bf16(af[mt], bfr[nt], acc[mt][nt], 0, 0, 0);
    }
    #pragma unroll
    for (int mt = 0; mt < 2; ++mt) {
        const int row = mt * 16 + (l >> 4) * 4;
        #pragma unroll
        for (int nt = 0; nt < 2; ++nt)
            #pragma unroll
            for (int r = 0; r < 4; ++r)
                red[w][row + r][nt * 16 + lm] = acc[mt][nt][r];
    }
    __syncthreads();
    if (is_tp) {
        const int m = tid >> 3, n4 = (tid & 7) * 4;
        float4 v;
        float* vp = (float*)&v;
        #pragma unroll
        for (int j = 0; j < 4; ++j)
            vp[j] = red[0][m][n4 + j] + red[1][m][n4 + j] + red[2][m][n4 + j]
                  + red[3][m][n4 + j] + b1[n0 + n4 + j];
        *(float4*)&tp[(size_t)(m0 + m) * 1024 + n0 + n4] = v;
    } else {
        // quad-pack: thread -> (a = tid>>3, q = tid&7), h-local = q*4..+3
        const int a = tid >> 3, q = tid & 7;
        const int b = m0 >> 9, a0 = m0 & 511;
        bf16x4 v;
        #pragma unroll
        for (int c = 0; c < 4; ++c)
            v[c] = (bf16_t)(red[0][a][q * 4 + c] + red[1][a][q * 4 + c]
                          + red[2][a][q * 4 + c] + red[3][a][q * 4 + c]);
        const size_t hq = (size_t)(n0 >> 2) + q;
        *(bf16x4*)&apT4[(hq * 1024 + b * 512 + a0 + a) * 4] = v;
    }
}

// ---------------------------------------------------------------------------
// fused conv gemm: tile 16o x 32bt, 8 waves = i-chunks of 128, LDS reduce,
// bias/relu + GN stats + bf16 transposed write. Grid (8 btg, 64 og).
// ---------------------------------------------------------------------------
__global__ __launch_bounds__(512, 4) void conv_fused_k(
    const bf16_t* __restrict__ Wc, const bf16_t* __restrict__ xp,
    const float* __restrict__ bias, bf16_t* __restrict__ out,
    int rowsPerB, int rowOff, float* __restrict__ stats)
{
    __shared__ float red[8][16][36];
    __shared__ float sred[8], sredq[8];
    const int tid = threadIdx.x;
    const int w = tid >> 6, l = tid & 63;
    const int bt0 = blockIdx.x * 32, m0 = blockIdx.y * 16;
    const int i0 = w * 128;
    const int lm = l & 15, lk = (l >> 4) * 8;
    const int b = bt0 >> 7, tbase = bt0 & 127;
    f32x4 acc[2];
    acc[0] = (f32x4)(0.0f); acc[1] = (f32x4)(0.0f);
    const bf16_t* aq = Wc + (size_t)(m0 + lm) * 1024 + i0 + lk;
    const bf16_t* bq = xp + (size_t)(b * 130 + tbase + lm) * 1024 + i0 + lk;
    #pragma unroll
    for (int r = 0; r < 3; ++r) {
        const bf16_t* ar = aq + (size_t)r * 1048576;
        const bf16_t* br = bq + (size_t)r * 1024;
        #pragma unroll
        for (int kk = 0; kk < 128; kk += 32) {
            bf16x8 af = *(const bf16x8*)(ar + kk);
            bf16x8 bf0 = *(const bf16x8*)(br + kk);
            bf16x8 bf1 = *(const bf16x8*)(br + 16384 + kk);
            acc[0] = __builtin_amdgcn_mfma_f32_16x16x32_bf16(af, bf0, acc[0], 0, 0, 0);
            acc[1] = __builtin_amdgcn_mfma_f32_16x16x32_bf16(af, bf1, acc[1], 0, 0, 0);
        }
    }
    #pragma unroll
    for (int nt = 0; nt < 2; ++nt) {
        const int row = (l >> 4) * 4;
        #pragma unroll
        for (int r = 0; r < 4; ++r)
            red[w][row + r][nt * 16 + lm] = acc[nt][r];
    }
    __syncthreads();
    // reduce 8 waves; one cell per thread (16x32 = 512)
    const int m = tid >> 5, n = tid & 31;
    float v = 0.f;
    #pragma unroll
    for (int ww = 0; ww < 8; ++ww) v += red[ww][m][n];
    v = fmaxf(v + bias[m0 + m], 0.f);
    float s = v, q = v * v;
    __syncthreads();
    red[0][m][n] = v;
    // GN stats: wave reduce -> LDS -> single atomic pair
    #pragma unroll
    for (int off = 32; off > 0; off >>= 1) {
        s += __shfl_xor(s, off);
        q += __shfl_xor(q, off);
    }
    if (l == 0) { sred[w] = s; sredq[w] = q; }
    __syncthreads();
    if (tid == 0) {
        float ts = 0.f, tq = 0.f;
        #pragma unroll
        for (int ww = 0; ww < 8; ++ww) { ts += sred[ww]; tq += sredq[ww]; }
        atomicAdd(&stats[b * 2], ts);
        atomicAdd(&stats[b * 2 + 1], tq);
    }
    // transposed write: out[bt][o], 64 threads x bf16x8
    if (tid < 64) {
        const int row = tid >> 1, half = tid & 1;
        bf16x8 o8;
        #pragma unroll
        for (int j = 0; j < 8; ++j) o8[j] = (bf16_t)red[0][half * 8 + j][row];
        const int t = tbase + row;
        *(bf16x8*)&out[(size_t)(b * rowsPerB + rowOff + t) * 1024 + m0 + half * 8] = o8;
    }
}

// GroupNorm apply in-place on padded bf16 buffer (conv1 only)
__global__ __launch_bounds__(256) void gn_apply_k(
    bf16_t* __restrict__ buf, const float* __restrict__ stats,
    const float* __restrict__ g, const float* __restrict__ bet)
{
    const int idx4 = blockIdx.x * 256 + threadIdx.x;
    const int e = idx4 * 4;
    const int bt = e >> 10, o = e & 1023;
    const int b = bt >> 7, t = bt & 127;
    bf16_t* p = buf + (size_t)(b * 130 + 1 + t) * 1024 + o;
    const float cnt = 131072.f;
    const float mu = stats[b * 2] / cnt;
    const float var = stats[b * 2 + 1] / cnt - mu * mu;
    const float rs = rsqrtf(var + EPSV);
    bf16x4 v = *(bf16x4*)p;
    float4 gv = *(const float4*)&g[o];
    float4 bv = *(const float4*)&bet[o];
    bf16x4 ov;
    ov[0] = (bf16_t)(((float)v[0] - mu) * rs * gv.x + bv.x);
    ov[1] = (bf16_t)(((float)v[1] - mu) * rs * gv.y + bv.y);
    ov[2] = (bf16_t)(((float)v[2] - mu) * rs * gv.z + bv.z);
    ov[3] = (bf16_t)(((float)v[3] - mu) * rs * gv.w + bv.w);
    *(bf16x4*)p = ov;
}

// ---------------------------------------------------------------------------
// logits partials: lp[hc][bt][a] = sum_{h in chunk} relu(tp[bt,h]+ap[h,a])*w2[h]
// grid (256 bt, 4 hc) x 512 threads (a). apT4 quad-packed: one 8B load = 4 h.
// ---------------------------------------------------------------------------
__global__ __launch_bounds__(512) void logits_k(
    const float* __restrict__ tp, const bf16_t* __restrict__ apT4,
    const float* __restrict__ w2, float* __restrict__ lp)
{
    const int bt = blockIdx.x, hc = blockIdx.y;
    const int b = bt >> 7;
    const int a = threadIdx.x;
    const float* tpr = tp + (size_t)bt * 1024 + hc * 256;   // wave-uniform
    const float* w2r = w2 + hc * 256;
    const bf16_t* apc = apT4 + ((size_t)(hc * 64) * 1024 + b * 512 + a) * 4;
    float acc = 0.f;
    #pragma unroll 4
    for (int hq = 0; hq < 64; hq += 2) {                    // 8 h per iter
        bf16x4 a0 = *(const bf16x4*)(apc + (size_t)hq * 4096);
        bf16x4 a1 = *(const bf16x4*)(apc + (size_t)(hq + 1) * 4096);
        float4 t0 = *(const float4*)&tpr[hq * 4];
        float4 t1 = *(const float4*)&tpr[hq * 4 + 4];
        float4 w0 = *(const float4*)&w2r[hq * 4];
        float4 w1 = *(const float4*)&w2r[hq * 4 + 4];
        acc += fmaxf(t0.x + (float)a0[0], 0.f) * w0.x;
        acc += fmaxf(t0.y + (float)a0[1], 0.f) * w0.y;
        acc += fmaxf(t0.z + (float)a0[2], 0.f) * w0.z;
        acc += fmaxf(t0.w + (float)a0[3], 0.f) * w0.w;
        acc += fmaxf(t1.x + (float)a1[0], 0.f) * w1.x;
        acc += fmaxf(t1.y + (float)a1[1], 0.f) * w1.y;
        acc += fmaxf(t1.z + (float)a1[2], 0.f) * w1.z;
        acc += fmaxf(t1.w + (float)a1[3], 0.f) * w1.w;
    }
    lp[(size_t)(hc * 256 + bt) * 512 + a] = acc;
}

// ---------------------------------------------------------------------------
// combine: blocks [0,256): sum lp chunks + bias + monotonic, softmax -> out.
//          blocks [256,288): conv3 + GN2-fold + softplus -> durations.
// ---------------------------------------------------------------------------
__global__ __launch_bounds__(512) void combine_k(
    const float* __restrict__ lp, const float* __restrict__ b2,
    const bf16_t* __restrict__ y2, const float* __restrict__ stats2,
    const float* __restrict__ g, const float* __restrict__ bet,
    const float* __restrict__ w3, const float* __restrict__ b3,
    float* __restrict__ out)
{
    __shared__ float redm[8], redsum[8];
    const int bid = blockIdx.x;
    const int tid = threadIdx.x;
    if (bid < 256) {
        const int bt = bid, t = bt & 127;
        const int a = tid;
        const int lane = a & 63, wid = a >> 6;
        const size_t base = (size_t)bt * 512 + a;
        float v = lp[base] + lp[131072 + base] + lp[262144 + base] + lp[393216 + base];
        v += b2[0] - 0.1f * fabsf((float)a - 4.0f * (float)t);
        float m = v;
        #pragma unroll
        for (int off = 32; off > 0; off >>= 1) m = fmaxf(m, __shfl_xor(m, off));
        if (lane == 0) redm[wid] = m;
        __syncthreads();
        float M = redm[0];
        #pragma unroll
        for (int i = 1; i < 8; ++i) M = fmaxf(M, redm[i]);
        const float e = expf(v - M);
        float s = e;
        #pragma unroll
        for (int off = 32; off > 0; off >>= 1) s += __shfl_xor(s, off);
        if (lane == 0) redsum[wid] = s;
        __syncthreads();
        float S = redsum[0];
        #pragma unroll
        for (int i = 1; i < 8; ++i) S += redsum[i];
        out[(size_t)bt * 512 + a] = e * (1.0f / S);
    } else {
        const int lane = tid & 63, w = tid >> 6;
        const int bt = (bid - 256) * 8 + w;
        const int b = bt >> 7;
        const float cnt = 131072.f;
        const float mu = stats2[b * 2] / cnt;
        const float var = stats2[b * 2 + 1] / cnt - mu * mu;
        const float rs = rsqrtf(var + EPSV);
        const bf16_t* row = y2 + (size_t)bt * 1024 + lane * 16;
        float s1 = 0.f, s2 = 0.f, s3 = 0.f;
        #pragma unroll
        for (int c = 0; c < 2; ++c) {
            bf16x8 yv = *(const bf16x8*)(row + c * 8);
            #pragma unroll
            for (int j = 0; j < 8; ++j) {
                const int i = lane * 16 + c * 8 + j;
                const float gw = g[i] * w3[i];
                s1 += gw * (float)yv[j];
                s2 += gw;
                s3 += bet[i] * w3[i];
            }
        }
        #pragma unroll
        for (int off = 32; off > 0; off >>= 1) {
            s1 += __shfl_xor(s1, off);
            s2 += __shfl_xor(s2, off);
            s3 += __shfl_xor(s3, off);
        }
        if (lane == 0) {
            const float t = rs * (s1 - mu * s2) + s3 + b3[0];
            out[131072 + bt] = fmaxf(t, 0.f) + log1pf(expf(-fabsf(t)));
        }
    }
}

extern "C" void kernel_launch(void* const* d_in, const int* in_sizes, int n_in,
                              void* d_out, int out_size, void* d_ws, size_t ws_size,
                              hipStream_t stream) {
    const float* text   = (const float*)d_in[0];
    const float* audio  = (const float*)d_in[1];
    const float* a_w1   = (const float*)d_in[2];
    const float* a_b1   = (const float*)d_in[3];
    const float* a_w2   = (const float*)d_in[4];
    const float* a_b2   = (const float*)d_in[5];
    const float* d_w1   = (const float*)d_in[6];
    const float* d_b1   = (const float*)d_in[7];
    const float* gn1_g  = (const float*)d_in[8];
    const float* gn1_b  = (const float*)d_in[9];
    const float* d_w2   = (const float*)d_in[10];
    const float* d_b2   = (const float*)d_in[11];
    const float* gn2_g  = (const float*)d_in[12];
    const float* gn2_b  = (const float*)d_in[13];
    const float* d_w3   = (const float*)d_in[14];
    const float* d_b3   = (const float*)d_in[15];

    char* ws = (char*)d_ws;
    float* outf = (float*)d_out;

    bf16_t* text_bf  = (bf16_t*)(ws + OFF_TEXTBF);
    bf16_t* audio_bf = (bf16_t*)(ws + OFF_AUDIOBF);
    bf16_t* w1topT   = (bf16_t*)(ws + OFF_W1TOP);
    bf16_t* w1botT   = (bf16_t*)(ws + OFF_W1BOT);
    bf16_t* wc1      = (bf16_t*)(ws + OFF_WC1);   // overlays stage1 after gemms
    bf16_t* wc2      = (bf16_t*)(ws + OFF_WC2);
    float*  tp       = (float*) (ws + OFF_TP);
    bf16_t* apT4     = (bf16_t*)(ws + OFF_APT);
    bf16_t* xp0      = (bf16_t*)(ws + OFF_XP0);
    bf16_t* xp1      = (bf16_t*)(ws + OFF_XP1);
    bf16_t* y2       = (bf16_t*)(ws + OFF_Y2);
    float*  stats    = (float*) (ws + OFF_STATS);
    float*  lp       = (float*) (ws + OFF_LP);    // overlays Wc1 after conv1

    // 1: cvt activations + w1 transpose + zero pads/stats
    prep_k<<<dim3(3329), 256, 0, stream>>>(text, audio, a_w1, text_bf, xp0,
                                           audio_bf, w1topT, w1botT, xp1, stats);
    // 2: tp (f32, bias folded) + apT4 (bf16 quad-packed) GEMMs, in-LDS split-k
    gemm_tpap_k<<<dim3(1280), 256, 0, stream>>>(text_bf, w1topT, a_b1, tp,
                                                audio_bf, w1botT, apT4);
    // 3: conv weights (both) -> Wc1/Wc2
    cvt_wc_k<<<dim3(2048), 256, 0, stream>>>(d_w1, d_w2, wc1, wc2);
    // 4: conv1 fused (8-wave split-k gemm + bias/relu + stats + transposed write)
    conv_fused_k<<<dim3(8, 64), 512, 0, stream>>>(wc1, xp0, d_b1, xp1, 130, 1, stats);
    // 5: GN1 apply
    gn_apply_k<<<dim3(256), 256, 0, stream>>>(xp1, stats, gn1_g, gn1_b);
    // 6: conv2 fused -> y2 (pre-GN2)
    conv_fused_k<<<dim3(8, 64), 512, 0, stream>>>(wc2, xp1, d_b2, y2, 128, 0, stats + 4);
    // 7: logits partials (h-split x4; lp overlays dead Wc1)
    logits_k<<<dim3(256, 4), 512, 0, stream>>>(tp, apT4, a_w2, lp);
    // 8: combine+softmax -> alignment; conv3+GN2fold+softplus -> durations
    combine_k<<<dim3(288), 512, 0, stream>>>(lp, a_b2, y2, stats + 4,
                                             gn2_g, gn2_b, d_w3, d_b3, outf);
}

// Round 8
// 206.581 us; speedup vs baseline: 1.2126x; 1.0112x over previous
//
#include <hip/hip_runtime.h>
#include <hip/hip_bf16.h>

// ---------------------------------------------------------------------------
// MonotonicAlignmentSearch R8: R7's packed-f16 dot2 logits, with cvt_wc
// restored as a separate dispatch AFTER gemm_tpap (fixes the R7 lifetime race:
// wc1 overlays stage-1 buffers, so it must be written only after tp/ap GEMMs).
// B=2, TT=128, TA=512, H=1024.
// ---------------------------------------------------------------------------

typedef __bf16 bf16_t;
typedef __bf16 bf16x8 __attribute__((ext_vector_type(8)));
typedef __bf16 bf16x4 __attribute__((ext_vector_type(4)));
typedef float  f32x4  __attribute__((ext_vector_type(4)));
typedef _Float16 f16_t;
typedef _Float16 f16x2 __attribute__((ext_vector_type(2)));
typedef _Float16 f16x4 __attribute__((ext_vector_type(4)));

#define EPSV 1e-5f

// ---- workspace offsets (bytes), total 17842208 (== proven-good size) ------
#define OFF_TEXTBF   0u          //  524288  bf16 text [256][1024]      (stage1)
#define OFF_AUDIOBF  524288u     // 2097152  bf16 audio [1024][1024]    (stage1)
#define OFF_W1TOP    2621440u    // 2097152  bf16 W1topT [1024][1024]   (stage1)
#define OFF_W1BOT    4718592u    // 2097152  bf16 W1botT [1024][1024]   (stage1)
#define OFF_WC1      0u          // 6291456  bf16 Wc1 (overlays stage1; write
                                 //          only AFTER gemm_tpap consumed it)
#define OFF_WC2      6815744u    // 6291456  bf16 Wc2
#define OFF_TP       13107200u   //  524288  f16 tp [256][1024] (bias folded)
#define OFF_W2F      13631488u   //    2048  f16 w2 [1024]
#define OFF_APT      14155776u   // 2097152  f16 apT4 [256 hq][1024 ba][4]
#define OFF_XP0      16252928u   //  532480  bf16 xp0 [2][130][1024]
#define OFF_XP1      16785408u   //  532480  bf16 xp1 [2][130][1024]
#define OFF_Y2       17317888u   //  524288  bf16 y2 [256][1024] (pre-GN2)
#define OFF_STATS    17842176u   //      32  8 f32 GN stats
#define OFF_LP       0u          // 2097152  f32 lp [4 hc][256 bt][512 a]
                                 //          (overlays Wc1; Wc1 dead after conv1)

// ---------------------------------------------------------------------------
// prep: [0,1280) cvt activations; [1280,3328) w1 transpose-cast;
// 3328: zero pads + stats + w2->f16.  (NO wc writes here — lifetime!)
// ---------------------------------------------------------------------------
__global__ __launch_bounds__(256) void prep_k(
    const float* __restrict__ text, const float* __restrict__ audio,
    const float* __restrict__ w1, const float* __restrict__ w2,
    bf16_t* __restrict__ text_bf, bf16_t* __restrict__ xp0,
    bf16_t* __restrict__ audio_bf,
    bf16_t* __restrict__ topT, bf16_t* __restrict__ botT,
    bf16_t* __restrict__ xp1, float* __restrict__ stats,
    f16_t* __restrict__ w2f)
{
    __shared__ float tile[32][33];
    const int bid = blockIdx.x;
    if (bid < 1280) {
        const int e = (bid * 256 + threadIdx.x) * 4;   // 1310720 total
        if (e < 262144) {
            float4 v = *(const float4*)&text[e];
            bf16x4 o; o[0] = (bf16_t)v.x; o[1] = (bf16_t)v.y; o[2] = (bf16_t)v.z; o[3] = (bf16_t)v.w;
            *(bf16x4*)&text_bf[e] = o;
            const int bt = e >> 10, h = e & 1023;
            const int b = bt >> 7, t = bt & 127;
            *(bf16x4*)&xp0[(size_t)(b * 130 + 1 + t) * 1024 + h] = o;
        } else {
            const int ea = e - 262144;
            float4 v = *(const float4*)&audio[ea];
            bf16x4 o; o[0] = (bf16_t)v.x; o[1] = (bf16_t)v.y; o[2] = (bf16_t)v.z; o[3] = (bf16_t)v.w;
            *(bf16x4*)&audio_bf[ea] = o;
        }
    } else if (bid < 3328) {
        const int b2 = bid - 1280;
        const int bx = b2 & 31, by = b2 >> 5;          // (32, 64)
        const int tx = threadIdx.x & 31, ty = threadIdx.x >> 5;
        #pragma unroll
        for (int j = 0; j < 4; ++j)
            tile[ty + j * 8][tx] = w1[(size_t)(by * 32 + ty + j * 8) * 1024 + bx * 32 + tx];
        __syncthreads();
        bf16_t* out = (by < 32) ? topT : botT;
        const int hbase = (by & 31) * 32;
        #pragma unroll
        for (int j = 0; j < 4; ++j) {
            const int d = bx * 32 + ty + j * 8;
            out[(size_t)d * 1024 + hbase + tx] = (bf16_t)tile[tx][ty + j * 8];
        }
    } else {
        const int tid = threadIdx.x;
        const int rowmap[4] = {0, 129, 130, 259};
        const int f = tid * 16;
        const int r = f >> 10, w = f & 1023;
        bf16x8 z8 = (bf16x8)(bf16_t)0.0f;
        bf16_t* p0 = xp0 + (size_t)rowmap[r] * 1024 + w;
        bf16_t* p1 = xp1 + (size_t)rowmap[r] * 1024 + w;
        *(bf16x8*)p0 = z8; *(bf16x8*)(p0 + 8) = z8;
        *(bf16x8*)p1 = z8; *(bf16x8*)(p1 + 8) = z8;
        if (tid < 8) stats[tid] = 0.0f;
        float4 wv = *(const float4*)&w2[tid * 4];
        f16x4 wo; wo[0] = (f16_t)wv.x; wo[1] = (f16_t)wv.y; wo[2] = (f16_t)wv.z; wo[3] = (f16_t)wv.w;
        *(f16x4*)&w2f[tid * 4] = wo;
    }
}

// d_w1/d_w2 [1024][1024*3] fp32 ([o][i][r]) -> Wc [3][1024][1024] bf16 ([r][o][i])
// Launched AFTER gemm_tpap_k: wc1 overlays the then-dead stage-1 buffers.
__global__ __launch_bounds__(256) void cvt_wc_k(
    const float* __restrict__ w1c, const float* __restrict__ w2c,
    bf16_t* __restrict__ wc1, bf16_t* __restrict__ wc2)
{
    int bid = blockIdx.x;
    const float* w = (bid < 1024) ? w1c : w2c;
    bf16_t* wc = (bid < 1024) ? wc1 : wc2;
    bid &= 1023;
    const int t = bid * 256 + threadIdx.x;
    const int o = t >> 8, i4 = t & 255;
    const float* src = w + (size_t)o * 3072 + i4 * 12;
    float4 v0 = *(const float4*)&src[0];
    float4 v1 = *(const float4*)&src[4];
    float4 v2 = *(const float4*)&src[8];
    const float f[12] = {v0.x, v0.y, v0.z, v0.w, v1.x, v1.y, v1.z, v1.w, v2.x, v2.y, v2.z, v2.w};
    #pragma unroll
    for (int r = 0; r < 3; ++r) {
        bf16x4 o4;
        #pragma unroll
        for (int j = 0; j < 4; ++j) o4[j] = (bf16_t)f[j * 3 + r];
        *(bf16x4*)&wc[(size_t)r * 1048576 + (size_t)o * 1024 + i4 * 4] = o4;
    }
}

// ---------------------------------------------------------------------------
// tp+ap GEMM: 32x32 wave tiles, 4 waves/block = k-chunks of 256, LDS reduce.
// blocks [0,256): tp = f16(text@W1top + b1).  [256,1280): apT4 f16 quad-packed.
// ---------------------------------------------------------------------------
__global__ __launch_bounds__(256, 4) void gemm_tpap_k(
    const bf16_t* __restrict__ text_bf, const bf16_t* __restrict__ w1topT,
    const float* __restrict__ b1, f16_t* __restrict__ tp,
    const bf16_t* __restrict__ audio_bf, const bf16_t* __restrict__ w1botT,
    f16_t* __restrict__ apT4)
{
    __shared__ float red[4][32][36];
    const int bid = blockIdx.x;
    const int is_tp = (bid < 256) ? 1 : 0;
    const int b2 = is_tp ? bid : bid - 256;
    const int n0 = (b2 & 31) * 32, m0 = (b2 >> 5) * 32;
    const int tid = threadIdx.x;
    const int w = tid >> 6, l = tid & 63;
    const int lm = l & 15, lk = (l >> 4) * 8;
    const int k0 = w * 256;
    const bf16_t* A  = is_tp ? text_bf : audio_bf;
    const bf16_t* Bt = is_tp ? w1topT : w1botT;
    f32x4 acc[2][2];
    #pragma unroll
    for (int mt = 0; mt < 2; ++mt)
        #pragma unroll
        for (int nt = 0; nt < 2; ++nt) acc[mt][nt] = (f32x4)(0.0f);
    const bf16_t* Ap = A + (size_t)(m0 + lm) * 1024 + k0 + lk;
    const bf16_t* Bp = Bt + (size_t)(n0 + lm) * 1024 + k0 + lk;
    #pragma unroll
    for (int kk = 0; kk < 256; kk += 32) {
        bf16x8 af[2], bfr[2];
        #pragma unroll
        for (int i = 0; i < 2; ++i) af[i] = *(const bf16x8*)(Ap + (size_t)i * 16384 + kk);
        #pragma unroll
        for (int i = 0; i < 2; ++i) bfr[i] = *(const bf16x8*)(Bp + (size_t)i * 16384 + kk);
        #pragma unroll
        for (int mt = 0; mt < 2; ++mt)
            #pragma unroll
            for (int nt = 0; nt < 2; ++nt)
                acc[mt][nt] = __builtin_amdgcn_mfma_f32_16x16x32_bf16(af[mt], bfr[nt], acc[mt][nt], 0, 0, 0);
    }
    #pragma unroll
    for (int mt = 0; mt < 2; ++mt) {
        const int row = mt * 16 + (l >> 4) * 4;
        #pragma unroll
        for (int nt = 0; nt < 2; ++nt)
            #pragma unroll
            for (int r = 0; r < 4; ++r)
                red[w][row + r][nt * 16 + lm] = acc[mt][nt][r];
    }
    __syncthreads();
    if (is_tp) {
        const int m = tid >> 3, n4 = (tid & 7) * 4;
        f16x4 v;
        #pragma unroll
        for (int j = 0; j < 4; ++j)
            v[j] = (f16_t)(red[0][m][n4 + j] + red[1][m][n4 + j] + red[2][m][n4 + j]
                         + red[3][m][n4 + j] + b1[n0 + n4 + j]);
        *(f16x4*)&tp[(size_t)(m0 + m) * 1024 + n0 + n4] = v;
    } else {
        const int a = tid >> 3, q = tid & 7;
        const int b = m0 >> 9, a0 = m0 & 511;
        f16x4 v;
        #pragma unroll
        for (int c = 0; c < 4; ++c)
            v[c] = (f16_t)(red[0][a][q * 4 + c] + red[1][a][q * 4 + c]
                         + red[2][a][q * 4 + c] + red[3][a][q * 4 + c]);
        const size_t hq = (size_t)(n0 >> 2) + q;
        *(f16x4*)&apT4[(hq * 1024 + b * 512 + a0 + a) * 4] = v;
    }
}

// ---------------------------------------------------------------------------
// fused conv gemm: tile 16o x 32bt, 8 waves = i-chunks of 128, LDS reduce,
// bias/relu + GN stats + bf16 transposed write. Grid (8 btg, 64 og).
// ---------------------------------------------------------------------------
__global__ __launch_bounds__(512, 4) void conv_fused_k(
    const bf16_t* __restrict__ Wc, const bf16_t* __restrict__ xp,
    const float* __restrict__ bias, bf16_t* __restrict__ out,
    int rowsPerB, int rowOff, float* __restrict__ stats)
{
    __shared__ float red[8][16][36];
    __shared__ float sred[8], sredq[8];
    const int tid = threadIdx.x;
    const int w = tid >> 6, l = tid & 63;
    const int bt0 = blockIdx.x * 32, m0 = blockIdx.y * 16;
    const int i0 = w * 128;
    const int lm = l & 15, lk = (l >> 4) * 8;
    const int b = bt0 >> 7, tbase = bt0 & 127;
    f32x4 acc[2];
    acc[0] = (f32x4)(0.0f); acc[1] = (f32x4)(0.0f);
    const bf16_t* aq = Wc + (size_t)(m0 + lm) * 1024 + i0 + lk;
    const bf16_t* bq = xp + (size_t)(b * 130 + tbase + lm) * 1024 + i0 + lk;
    #pragma unroll
    for (int r = 0; r < 3; ++r) {
        const bf16_t* ar = aq + (size_t)r * 1048576;
        const bf16_t* br = bq + (size_t)r * 1024;
        #pragma unroll
        for (int kk = 0; kk < 128; kk += 32) {
            bf16x8 af = *(const bf16x8*)(ar + kk);
            bf16x8 bf0 = *(const bf16x8*)(br + kk);
            bf16x8 bf1 = *(const bf16x8*)(br + 16384 + kk);
            acc[0] = __builtin_amdgcn_mfma_f32_16x16x32_bf16(af, bf0, acc[0], 0, 0, 0);
            acc[1] = __builtin_amdgcn_mfma_f32_16x16x32_bf16(af, bf1, acc[1], 0, 0, 0);
        }
    }
    #pragma unroll
    for (int nt = 0; nt < 2; ++nt) {
        const int row = (l >> 4) * 4;
        #pragma unroll
        for (int r = 0; r < 4; ++r)
            red[w][row + r][nt * 16 + lm] = acc[nt][r];
    }
    __syncthreads();
    const int m = tid >> 5, n = tid & 31;
    float v = 0.f;
    #pragma unroll
    for (int ww = 0; ww < 8; ++ww) v += red[ww][m][n];
    v = fmaxf(v + bias[m0 + m], 0.f);
    float s = v, q = v * v;
    __syncthreads();
    red[0][m][n] = v;
    #pragma unroll
    for (int off = 32; off > 0; off >>= 1) {
        s += __shfl_xor(s, off);
        q += __shfl_xor(q, off);
    }
    if (l == 0) { sred[w] = s; sredq[w] = q; }
    __syncthreads();
    if (tid == 0) {
        float ts = 0.f, tq = 0.f;
        #pragma unroll
        for (int ww = 0; ww < 8; ++ww) { ts += sred[ww]; tq += sredq[ww]; }
        atomicAdd(&stats[b * 2], ts);
        atomicAdd(&stats[b * 2 + 1], tq);
    }
    if (tid < 64) {
        const int row = tid >> 1, half = tid & 1;
        bf16x8 o8;
        #pragma unroll
        for (int j = 0; j < 8; ++j) o8[j] = (bf16_t)red[0][half * 8 + j][row];
        const int t = tbase + row;
        *(bf16x8*)&out[(size_t)(b * rowsPerB + rowOff + t) * 1024 + m0 + half * 8] = o8;
    }
}

// GroupNorm apply in-place on padded bf16 buffer (conv1 only)
__global__ __launch_bounds__(256) void gn_apply_k(
    bf16_t* __restrict__ buf, const float* __restrict__ stats,
    const float* __restrict__ g, const float* __restrict__ bet)
{
    const int idx4 = blockIdx.x * 256 + threadIdx.x;
    const int e = idx4 * 4;
    const int bt = e >> 10, o = e & 1023;
    const int b = bt >> 7, t = bt & 127;
    bf16_t* p = buf + (size_t)(b * 130 + 1 + t) * 1024 + o;
    const float cnt = 131072.f;
    const float mu = stats[b * 2] / cnt;
    const float var = stats[b * 2 + 1] / cnt - mu * mu;
    const float rs = rsqrtf(var + EPSV);
    bf16x4 v = *(bf16x4*)p;
    float4 gv = *(const float4*)&g[o];
    float4 bv = *(const float4*)&bet[o];
    bf16x4 ov;
    ov[0] = (bf16_t)(((float)v[0] - mu) * rs * gv.x + bv.x);
    ov[1] = (bf16_t)(((float)v[1] - mu) * rs * gv.y + bv.y);
    ov[2] = (bf16_t)(((float)v[2] - mu) * rs * gv.z + bv.z);
    ov[3] = (bf16_t)(((float)v[3] - mu) * rs * gv.w + bv.w);
    *(bf16x4*)p = ov;
}

// ---------------------------------------------------------------------------
// logits partials, packed f16: lp[hc][bt][a] = sum relu(tp+ap)*w2 via
// pk_add + pk_max + v_dot2_f32_f16. grid (256 bt, 4 hc) x 512 threads (a).
// ---------------------------------------------------------------------------
__device__ __forceinline__ float dot2_acc(f16x2 x, f16x2 w, float acc) {
#if __has_builtin(__builtin_amdgcn_fdot2)
    return __builtin_amdgcn_fdot2(x, w, acc, false);
#else
    return acc + (float)x[0] * (float)w[0] + (float)x[1] * (float)w[1];
#endif
}

__global__ __launch_bounds__(512) void logits_k(
    const f16_t* __restrict__ tp, const f16_t* __restrict__ apT4,
    const f16_t* __restrict__ w2f, float* __restrict__ lp)
{
    const int bt = blockIdx.x, hc = blockIdx.y;
    const int b = bt >> 7;
    const int a = threadIdx.x;
    const f16_t* tpr = tp + (size_t)bt * 1024 + hc * 256;   // wave-uniform
    const f16_t* w2r = w2f + hc * 256;
    const f16_t* apc = apT4 + ((size_t)(hc * 64) * 1024 + b * 512 + a) * 4;
    float acc = 0.f;
    const f16x2 zero = (f16x2)(f16_t)0.0f;
    #pragma unroll 4
    for (int hq = 0; hq < 64; hq += 2) {                    // 8 h per iter
        f16x4 a0 = *(const f16x4*)(apc + (size_t)hq * 4096);
        f16x4 a1 = *(const f16x4*)(apc + (size_t)(hq + 1) * 4096);
        f16x4 t0 = *(const f16x4*)&tpr[hq * 4];
        f16x4 t1 = *(const f16x4*)&tpr[hq * 4 + 4];
        f16x4 w0 = *(const f16x4*)&w2r[hq * 4];
        f16x4 w1 = *(const f16x4*)&w2r[hq * 4 + 4];
        f16x2 p;
        p = __builtin_elementwise_max((f16x2){t0[0] + a0[0], t0[1] + a0[1]}, zero);
        acc = dot2_acc(p, (f16x2){w0[0], w0[1]}, acc);
        p = __builtin_elementwise_max((f16x2){t0[2] + a0[2], t0[3] + a0[3]}, zero);
        acc = dot2_acc(p, (f16x2){w0[2], w0[3]}, acc);
        p = __builtin_elementwise_max((f16x2){t1[0] + a1[0], t1[1] + a1[1]}, zero);
        acc = dot2_acc(p, (f16x2){w1[0], w1[1]}, acc);
        p = __builtin_elementwise_max((f16x2){t1[2] + a1[2], t1[3] + a1[3]}, zero);
        acc = dot2_acc(p, (f16x2){w1[2], w1[3]}, acc);
    }
    lp[(size_t)(hc * 256 + bt) * 512 + a] = acc;
}

// ---------------------------------------------------------------------------
// combine: blocks [0,256): sum lp chunks + bias + monotonic, softmax -> out.
//          blocks [256,288): conv3 + GN2-fold + softplus -> durations.
// ---------------------------------------------------------------------------
__global__ __launch_bounds__(512) void combine_k(
    const float* __restrict__ lp, const float* __restrict__ b2,
    const bf16_t* __restrict__ y2, const float* __restrict__ stats2,
    const float* __restrict__ g, const float* __restrict__ bet,
    const float* __restrict__ w3, const float* __restrict__ b3,
    float* __restrict__ out)
{
    __shared__ float redm[8], redsum[8];
    const int bid = blockIdx.x;
    const int tid = threadIdx.x;
    if (bid < 256) {
        const int bt = bid, t = bt & 127;
        const int a = tid;
        const int lane = a & 63, wid = a >> 6;
        const size_t base = (size_t)bt * 512 + a;
        float v = lp[base] + lp[131072 + base] + lp[262144 + base] + lp[393216 + base];
        v += b2[0] - 0.1f * fabsf((float)a - 4.0f * (float)t);
        float m = v;
        #pragma unroll
        for (int off = 32; off > 0; off >>= 1) m = fmaxf(m, __shfl_xor(m, off));
        if (lane == 0) redm[wid] = m;
        __syncthreads();
        float M = redm[0];
        #pragma unroll
        for (int i = 1; i < 8; ++i) M = fmaxf(M, redm[i]);
        const float e = expf(v - M);
        float s = e;
        #pragma unroll
        for (int off = 32; off > 0; off >>= 1) s += __shfl_xor(s, off);
        if (lane == 0) redsum[wid] = s;
        __syncthreads();
        float S = redsum[0];
        #pragma unroll
        for (int i = 1; i < 8; ++i) S += redsum[i];
        out[(size_t)bt * 512 + a] = e * (1.0f / S);
    } else {
        const int lane = tid & 63, w = tid >> 6;
        const int bt = (bid - 256) * 8 + w;
        const int b = bt >> 7;
        const float cnt = 131072.f;
        const float mu = stats2[b * 2] / cnt;
        const float var = stats2[b * 2 + 1] / cnt - mu * mu;
        const float rs = rsqrtf(var + EPSV);
        const bf16_t* row = y2 + (size_t)bt * 1024 + lane * 16;
        float s1 = 0.f, s2 = 0.f, s3 = 0.f;
        #pragma unroll
        for (int c = 0; c < 2; ++c) {
            bf16x8 yv = *(const bf16x8*)(row + c * 8);
            #pragma unroll
            for (int j = 0; j < 8; ++j) {
                const int i = lane * 16 + c * 8 + j;
                const float gw = g[i] * w3[i];
                s1 += gw * (float)yv[j];
                s2 += gw;
                s3 += bet[i] * w3[i];
            }
        }
        #pragma unroll
        for (int off = 32; off > 0; off >>= 1) {
            s1 += __shfl_xor(s1, off);
            s2 += __shfl_xor(s2, off);
            s3 += __shfl_xor(s3, off);
        }
        if (lane == 0) {
            const float t = rs * (s1 - mu * s2) + s3 + b3[0];
            out[131072 + bt] = fmaxf(t, 0.f) + log1pf(expf(-fabsf(t)));
        }
    }
}

extern "C" void kernel_launch(void* const* d_in, const int* in_sizes, int n_in,
                              void* d_out, int out_size, void* d_ws, size_t ws_size,
                              hipStream_t stream) {
    const float* text   = (const float*)d_in[0];
    const float* audio  = (const float*)d_in[1];
    const float* a_w1   = (const float*)d_in[2];
    const float* a_b1   = (const float*)d_in[3];
    const float* a_w2   = (const float*)d_in[4];
    const float* a_b2   = (const float*)d_in[5];
    const float* d_w1   = (const float*)d_in[6];
    const float* d_b1   = (const float*)d_in[7];
    const float* gn1_g  = (const float*)d_in[8];
    const float* gn1_b  = (const float*)d_in[9];
    const float* d_w2   = (const float*)d_in[10];
    const float* d_b2   = (const float*)d_in[11];
    const float* gn2_g  = (const float*)d_in[12];
    const float* gn2_b  = (const float*)d_in[13];
    const float* d_w3   = (const float*)d_in[14];
    const float* d_b3   = (const float*)d_in[15];

    char* ws = (char*)d_ws;
    float* outf = (float*)d_out;

    bf16_t* text_bf  = (bf16_t*)(ws + OFF_TEXTBF);
    bf16_t* audio_bf = (bf16_t*)(ws + OFF_AUDIOBF);
    bf16_t* w1topT   = (bf16_t*)(ws + OFF_W1TOP);
    bf16_t* w1botT   = (bf16_t*)(ws + OFF_W1BOT);
    bf16_t* wc1      = (bf16_t*)(ws + OFF_WC1);   // overlays stage1 after gemms
    bf16_t* wc2      = (bf16_t*)(ws + OFF_WC2);
    f16_t*  tp       = (f16_t*) (ws + OFF_TP);
    f16_t*  w2f      = (f16_t*) (ws + OFF_W2F);
    f16_t*  apT4     = (f16_t*) (ws + OFF_APT);
    bf16_t* xp0      = (bf16_t*)(ws + OFF_XP0);
    bf16_t* xp1      = (bf16_t*)(ws + OFF_XP1);
    bf16_t* y2       = (bf16_t*)(ws + OFF_Y2);
    float*  stats    = (float*) (ws + OFF_STATS);
    float*  lp       = (float*) (ws + OFF_LP);    // overlays Wc1 after conv1

    // 1: cvt activations + w1 transpose + zero pads/stats + w2->f16
    prep_k<<<dim3(3329), 256, 0, stream>>>(text, audio, a_w1, a_w2, text_bf, xp0,
                                           audio_bf, w1topT, w1botT, xp1, stats, w2f);
    // 2: tp (f16, bias folded) + apT4 (f16 quad-packed) GEMMs, in-LDS split-k
    gemm_tpap_k<<<dim3(1280), 256, 0, stream>>>(text_bf, w1topT, a_b1, tp,
                                                audio_bf, w1botT, apT4);
    // 3: conv weights -> Wc1/Wc2 (AFTER gemm_tpap: wc1 overlays stage1 buffers)
    cvt_wc_k<<<dim3(2048), 256, 0, stream>>>(d_w1, d_w2, wc1, wc2);
    // 4: conv1 fused (8-wave split-k gemm + bias/relu + stats + transposed write)
    conv_fused_k<<<dim3(8, 64), 512, 0, stream>>>(wc1, xp0, d_b1, xp1, 130, 1, stats);
    // 5: GN1 apply
    gn_apply_k<<<dim3(256), 256, 0, stream>>>(xp1, stats, gn1_g, gn1_b);
    // 6: conv2 fused -> y2 (pre-GN2)
    conv_fused_k<<<dim3(8, 64), 512, 0, stream>>>(wc2, xp1, d_b2, y2, 128, 0, stats + 4);
    // 7: logits partials (packed f16 dot2; lp overlays dead Wc1)
    logits_k<<<dim3(256, 4), 512, 0, stream>>>(tp, apT4, w2f, lp);
    // 8: combine+softmax -> alignment; conv3+GN2fold+softplus -> durations
    combine_k<<<dim3(288), 512, 0, stream>>>(lp, a_b2, y2, stats + 4,
                                             gn2_g, gn2_b, d_w3, d_b3, outf);
}

// Round 9
// 201.130 us; speedup vs baseline: 1.2454x; 1.0271x over previous
//
#include <hip/hip_runtime.h>
#include <hip/hip_bf16.h>

// ---------------------------------------------------------------------------
// MonotonicAlignmentSearch R9: no overlays (ws is 256 MB — fills prove it),
// cvt_wc folded into prep (7 dispatches), logits 2-t-per-block (halved apT
// L2 traffic). B=2, TT=128, TA=512, H=1024.
// ---------------------------------------------------------------------------

typedef __bf16 bf16_t;
typedef __bf16 bf16x8 __attribute__((ext_vector_type(8)));
typedef __bf16 bf16x4 __attribute__((ext_vector_type(4)));
typedef float  f32x4  __attribute__((ext_vector_type(4)));
typedef _Float16 f16_t;
typedef _Float16 f16x2 __attribute__((ext_vector_type(2)));
typedef _Float16 f16x4 __attribute__((ext_vector_type(4)));

#define EPSV 1e-5f

// ---- workspace offsets (bytes) — NO overlays, total ~26.2 MB << 256 MB ----
#define OFF_TEXTBF   0u          //  524288  bf16 text [256][1024]
#define OFF_AUDIOBF  524288u     // 2097152  bf16 audio [1024][1024]
#define OFF_W1TOP    2621440u    // 2097152  bf16 W1topT [1024][1024]
#define OFF_W1BOT    4718592u    // 2097152  bf16 W1botT [1024][1024]
#define OFF_WC1      6815744u    // 6291456  bf16 Wc1 [3][1024][1024]
#define OFF_WC2      13107200u   // 6291456  bf16 Wc2 [3][1024][1024]
#define OFF_TP       19398656u   //  524288  f16 tp [256][1024] (bias folded)
#define OFF_W2F      19922944u   //    2048  f16 w2 [1024]
#define OFF_APT      20447232u   // 2097152  f16 apT4 [256 hq][1024 ba][4]
#define OFF_XP0      22544384u   //  532480  bf16 xp0 [2][130][1024]
#define OFF_XP1      23076864u   //  532480  bf16 xp1 [2][130][1024]
#define OFF_Y2       23609344u   //  524288  bf16 y2 [256][1024] (pre-GN2)
#define OFF_STATS    24133632u   //      32  8 f32 GN stats
#define OFF_LP       24137728u   // 2097152  f32 lp [4 hc][256 bt][512 a]

// ---------------------------------------------------------------------------
// prep: [0,1280) cvt activations; [1280,3328) w1 transpose-cast;
// [3328,5376) conv-weight cvt (wc1/wc2 have private offsets — no race now);
// 5376: zero pads + stats + w2->f16.
// ---------------------------------------------------------------------------
__global__ __launch_bounds__(256) void prep_k(
    const float* __restrict__ text, const float* __restrict__ audio,
    const float* __restrict__ w1,
    const float* __restrict__ w1c, const float* __restrict__ w2c,
    const float* __restrict__ w2,
    bf16_t* __restrict__ text_bf, bf16_t* __restrict__ xp0,
    bf16_t* __restrict__ audio_bf,
    bf16_t* __restrict__ topT, bf16_t* __restrict__ botT,
    bf16_t* __restrict__ wc1, bf16_t* __restrict__ wc2,
    bf16_t* __restrict__ xp1, float* __restrict__ stats,
    f16_t* __restrict__ w2f)
{
    __shared__ float tile[32][33];
    const int bid = blockIdx.x;
    if (bid < 1280) {
        const int e = (bid * 256 + threadIdx.x) * 4;   // 1310720 total
        if (e < 262144) {
            float4 v = *(const float4*)&text[e];
            bf16x4 o; o[0] = (bf16_t)v.x; o[1] = (bf16_t)v.y; o[2] = (bf16_t)v.z; o[3] = (bf16_t)v.w;
            *(bf16x4*)&text_bf[e] = o;
            const int bt = e >> 10, h = e & 1023;
            const int b = bt >> 7, t = bt & 127;
            *(bf16x4*)&xp0[(size_t)(b * 130 + 1 + t) * 1024 + h] = o;
        } else {
            const int ea = e - 262144;
            float4 v = *(const float4*)&audio[ea];
            bf16x4 o; o[0] = (bf16_t)v.x; o[1] = (bf16_t)v.y; o[2] = (bf16_t)v.z; o[3] = (bf16_t)v.w;
            *(bf16x4*)&audio_bf[ea] = o;
        }
    } else if (bid < 3328) {
        const int b2 = bid - 1280;
        const int bx = b2 & 31, by = b2 >> 5;          // (32, 64)
        const int tx = threadIdx.x & 31, ty = threadIdx.x >> 5;
        #pragma unroll
        for (int j = 0; j < 4; ++j)
            tile[ty + j * 8][tx] = w1[(size_t)(by * 32 + ty + j * 8) * 1024 + bx * 32 + tx];
        __syncthreads();
        bf16_t* out = (by < 32) ? topT : botT;
        const int hbase = (by & 31) * 32;
        #pragma unroll
        for (int j = 0; j < 4; ++j) {
            const int d = bx * 32 + ty + j * 8;
            out[(size_t)d * 1024 + hbase + tx] = (bf16_t)tile[tx][ty + j * 8];
        }
    } else if (bid < 5376) {
        int b2 = bid - 3328;
        const float* w = (b2 < 1024) ? w1c : w2c;
        bf16_t* wc = (b2 < 1024) ? wc1 : wc2;
        b2 &= 1023;
        const int t = b2 * 256 + threadIdx.x;
        const int o = t >> 8, i4 = t & 255;
        const float* src = w + (size_t)o * 3072 + i4 * 12;
        float4 v0 = *(const float4*)&src[0];
        float4 v1 = *(const float4*)&src[4];
        float4 v2 = *(const float4*)&src[8];
        const float f[12] = {v0.x, v0.y, v0.z, v0.w, v1.x, v1.y, v1.z, v1.w, v2.x, v2.y, v2.z, v2.w};
        #pragma unroll
        for (int r = 0; r < 3; ++r) {
            bf16x4 o4;
            #pragma unroll
            for (int j = 0; j < 4; ++j) o4[j] = (bf16_t)f[j * 3 + r];
            *(bf16x4*)&wc[(size_t)r * 1048576 + (size_t)o * 1024 + i4 * 4] = o4;
        }
    } else {
        const int tid = threadIdx.x;
        const int rowmap[4] = {0, 129, 130, 259};
        const int f = tid * 16;
        const int r = f >> 10, w = f & 1023;
        bf16x8 z8 = (bf16x8)(bf16_t)0.0f;
        bf16_t* p0 = xp0 + (size_t)rowmap[r] * 1024 + w;
        bf16_t* p1 = xp1 + (size_t)rowmap[r] * 1024 + w;
        *(bf16x8*)p0 = z8; *(bf16x8*)(p0 + 8) = z8;
        *(bf16x8*)p1 = z8; *(bf16x8*)(p1 + 8) = z8;
        if (tid < 8) stats[tid] = 0.0f;
        float4 wv = *(const float4*)&w2[tid * 4];
        f16x4 wo; wo[0] = (f16_t)wv.x; wo[1] = (f16_t)wv.y; wo[2] = (f16_t)wv.z; wo[3] = (f16_t)wv.w;
        *(f16x4*)&w2f[tid * 4] = wo;
    }
}

// ---------------------------------------------------------------------------
// tp+ap GEMM: 32x32 wave tiles, 4 waves/block = k-chunks of 256, LDS reduce.
// blocks [0,256): tp = f16(text@W1top + b1).  [256,1280): apT4 f16 quad-packed.
// ---------------------------------------------------------------------------
__global__ __launch_bounds__(256, 4) void gemm_tpap_k(
    const bf16_t* __restrict__ text_bf, const bf16_t* __restrict__ w1topT,
    const float* __restrict__ b1, f16_t* __restrict__ tp,
    const bf16_t* __restrict__ audio_bf, const bf16_t* __restrict__ w1botT,
    f16_t* __restrict__ apT4)
{
    __shared__ float red[4][32][36];
    const int bid = blockIdx.x;
    const int is_tp = (bid < 256) ? 1 : 0;
    const int b2 = is_tp ? bid : bid - 256;
    const int n0 = (b2 & 31) * 32, m0 = (b2 >> 5) * 32;
    const int tid = threadIdx.x;
    const int w = tid >> 6, l = tid & 63;
    const int lm = l & 15, lk = (l >> 4) * 8;
    const int k0 = w * 256;
    const bf16_t* A  = is_tp ? text_bf : audio_bf;
    const bf16_t* Bt = is_tp ? w1topT : w1botT;
    f32x4 acc[2][2];
    #pragma unroll
    for (int mt = 0; mt < 2; ++mt)
        #pragma unroll
        for (int nt = 0; nt < 2; ++nt) acc[mt][nt] = (f32x4)(0.0f);
    const bf16_t* Ap = A + (size_t)(m0 + lm) * 1024 + k0 + lk;
    const bf16_t* Bp = Bt + (size_t)(n0 + lm) * 1024 + k0 + lk;
    #pragma unroll
    for (int kk = 0; kk < 256; kk += 32) {
        bf16x8 af[2], bfr[2];
        #pragma unroll
        for (int i = 0; i < 2; ++i) af[i] = *(const bf16x8*)(Ap + (size_t)i * 16384 + kk);
        #pragma unroll
        for (int i = 0; i < 2; ++i) bfr[i] = *(const bf16x8*)(Bp + (size_t)i * 16384 + kk);
        #pragma unroll
        for (int mt = 0; mt < 2; ++mt)
            #pragma unroll
            for (int nt = 0; nt < 2; ++nt)
                acc[mt][nt] = __builtin_amdgcn_mfma_f32_16x16x32_bf16(af[mt], bfr[nt], acc[mt][nt], 0, 0, 0);
    }
    #pragma unroll
    for (int mt = 0; mt < 2; ++mt) {
        const int row = mt * 16 + (l >> 4) * 4;
        #pragma unroll
        for (int nt = 0; nt < 2; ++nt)
            #pragma unroll
            for (int r = 0; r < 4; ++r)
                red[w][row + r][nt * 16 + lm] = acc[mt][nt][r];
    }
    __syncthreads();
    if (is_tp) {
        const int m = tid >> 3, n4 = (tid & 7) * 4;
        f16x4 v;
        #pragma unroll
        for (int j = 0; j < 4; ++j)
            v[j] = (f16_t)(red[0][m][n4 + j] + red[1][m][n4 + j] + red[2][m][n4 + j]
                         + red[3][m][n4 + j] + b1[n0 + n4 + j]);
        *(f16x4*)&tp[(size_t)(m0 + m) * 1024 + n0 + n4] = v;
    } else {
        const int a = tid >> 3, q = tid & 7;
        const int b = m0 >> 9, a0 = m0 & 511;
        f16x4 v;
        #pragma unroll
        for (int c = 0; c < 4; ++c)
            v[c] = (f16_t)(red[0][a][q * 4 + c] + red[1][a][q * 4 + c]
                         + red[2][a][q * 4 + c] + red[3][a][q * 4 + c]);
        const size_t hq = (size_t)(n0 >> 2) + q;
        *(f16x4*)&apT4[(hq * 1024 + b * 512 + a0 + a) * 4] = v;
    }
}

// ---------------------------------------------------------------------------
// fused conv gemm: tile 16o x 32bt, 8 waves = i-chunks of 128, LDS reduce,
// bias/relu + GN stats + bf16 transposed write. Grid (8 btg, 64 og).
// ---------------------------------------------------------------------------
__global__ __launch_bounds__(512, 4) void conv_fused_k(
    const bf16_t* __restrict__ Wc, const bf16_t* __restrict__ xp,
    const float* __restrict__ bias, bf16_t* __restrict__ out,
    int rowsPerB, int rowOff, float* __restrict__ stats)
{
    __shared__ float red[8][16][36];
    __shared__ float sred[8], sredq[8];
    const int tid = threadIdx.x;
    const int w = tid >> 6, l = tid & 63;
    const int bt0 = blockIdx.x * 32, m0 = blockIdx.y * 16;
    const int i0 = w * 128;
    const int lm = l & 15, lk = (l >> 4) * 8;
    const int b = bt0 >> 7, tbase = bt0 & 127;
    f32x4 acc[2];
    acc[0] = (f32x4)(0.0f); acc[1] = (f32x4)(0.0f);
    const bf16_t* aq = Wc + (size_t)(m0 + lm) * 1024 + i0 + lk;
    const bf16_t* bq = xp + (size_t)(b * 130 + tbase + lm) * 1024 + i0 + lk;
    #pragma unroll
    for (int r = 0; r < 3; ++r) {
        const bf16_t* ar = aq + (size_t)r * 1048576;
        const bf16_t* br = bq + (size_t)r * 1024;
        #pragma unroll
        for (int kk = 0; kk < 128; kk += 32) {
            bf16x8 af = *(const bf16x8*)(ar + kk);
            bf16x8 bf0 = *(const bf16x8*)(br + kk);
            bf16x8 bf1 = *(const bf16x8*)(br + 16384 + kk);
            acc[0] = __builtin_amdgcn_mfma_f32_16x16x32_bf16(af, bf0, acc[0], 0, 0, 0);
            acc[1] = __builtin_amdgcn_mfma_f32_16x16x32_bf16(af, bf1, acc[1], 0, 0, 0);
        }
    }
    #pragma unroll
    for (int nt = 0; nt < 2; ++nt) {
        const int row = (l >> 4) * 4;
        #pragma unroll
        for (int r = 0; r < 4; ++r)
            red[w][row + r][nt * 16 + lm] = acc[nt][r];
    }
    __syncthreads();
    const int m = tid >> 5, n = tid & 31;
    float v = 0.f;
    #pragma unroll
    for (int ww = 0; ww < 8; ++ww) v += red[ww][m][n];
    v = fmaxf(v + bias[m0 + m], 0.f);
    float s = v, q = v * v;
    __syncthreads();
    red[0][m][n] = v;
    #pragma unroll
    for (int off = 32; off > 0; off >>= 1) {
        s += __shfl_xor(s, off);
        q += __shfl_xor(q, off);
    }
    if (l == 0) { sred[w] = s; sredq[w] = q; }
    __syncthreads();
    if (tid == 0) {
        float ts = 0.f, tq = 0.f;
        #pragma unroll
        for (int ww = 0; ww < 8; ++ww) { ts += sred[ww]; tq += sredq[ww]; }
        atomicAdd(&stats[b * 2], ts);
        atomicAdd(&stats[b * 2 + 1], tq);
    }
    if (tid < 64) {
        const int row = tid >> 1, half = tid & 1;
        bf16x8 o8;
        #pragma unroll
        for (int j = 0; j < 8; ++j) o8[j] = (bf16_t)red[0][half * 8 + j][row];
        const int t = tbase + row;
        *(bf16x8*)&out[(size_t)(b * rowsPerB + rowOff + t) * 1024 + m0 + half * 8] = o8;
    }
}

// GroupNorm apply in-place on padded bf16 buffer (conv1 only)
__global__ __launch_bounds__(256) void gn_apply_k(
    bf16_t* __restrict__ buf, const float* __restrict__ stats,
    const float* __restrict__ g, const float* __restrict__ bet)
{
    const int idx4 = blockIdx.x * 256 + threadIdx.x;
    const int e = idx4 * 4;
    const int bt = e >> 10, o = e & 1023;
    const int b = bt >> 7, t = bt & 127;
    bf16_t* p = buf + (size_t)(b * 130 + 1 + t) * 1024 + o;
    const float cnt = 131072.f;
    const float mu = stats[b * 2] / cnt;
    const float var = stats[b * 2 + 1] / cnt - mu * mu;
    const float rs = rsqrtf(var + EPSV);
    bf16x4 v = *(bf16x4*)p;
    float4 gv = *(const float4*)&g[o];
    float4 bv = *(const float4*)&bet[o];
    bf16x4 ov;
    ov[0] = (bf16_t)(((float)v[0] - mu) * rs * gv.x + bv.x);
    ov[1] = (bf16_t)(((float)v[1] - mu) * rs * gv.y + bv.y);
    ov[2] = (bf16_t)(((float)v[2] - mu) * rs * gv.z + bv.z);
    ov[3] = (bf16_t)(((float)v[3] - mu) * rs * gv.w + bv.w);
    *(bf16x4*)p = ov;
}

// ---------------------------------------------------------------------------
// logits partials, packed f16, 2 t-rows per block (apT slice reused):
// lp[hc][bt][a] = sum_{h in chunk} relu(tp[bt,h]+ap[h,a])*w2[h]
// grid (128 btp, 4 hc) x 512 threads (a).
// ---------------------------------------------------------------------------
__device__ __forceinline__ float dot2_acc(f16x2 x, f16x2 w, float acc) {
#if __has_builtin(__builtin_amdgcn_fdot2)
    return __builtin_amdgcn_fdot2(x, w, acc, false);
#else
    return acc + (float)x[0] * (float)w[0] + (float)x[1] * (float)w[1];
#endif
}

__global__ __launch_bounds__(512) void logits_k(
    const f16_t* __restrict__ tp, const f16_t* __restrict__ apT4,
    const f16_t* __restrict__ w2f, float* __restrict__ lp)
{
    const int btp = blockIdx.x, hc = blockIdx.y;
    const int bt0 = btp * 2;
    const int b = bt0 >> 7;
    const int a = threadIdx.x;
    const f16_t* tpr0 = tp + (size_t)bt0 * 1024 + hc * 256;   // wave-uniform
    const f16_t* tpr1 = tpr0 + 1024;
    const f16_t* w2r = w2f + hc * 256;
    const f16_t* apc = apT4 + ((size_t)(hc * 64) * 1024 + b * 512 + a) * 4;
    float acc0 = 0.f, acc1 = 0.f;
    const f16x2 zero = (f16x2)(f16_t)0.0f;
    #pragma unroll 4
    for (int hq = 0; hq < 64; hq += 2) {                    // 8 h per iter
        f16x4 a0 = *(const f16x4*)(apc + (size_t)hq * 4096);
        f16x4 a1 = *(const f16x4*)(apc + (size_t)(hq + 1) * 4096);
        f16x4 t00 = *(const f16x4*)&tpr0[hq * 4];
        f16x4 t01 = *(const f16x4*)&tpr0[hq * 4 + 4];
        f16x4 t10 = *(const f16x4*)&tpr1[hq * 4];
        f16x4 t11 = *(const f16x4*)&tpr1[hq * 4 + 4];
        f16x4 w0 = *(const f16x4*)&w2r[hq * 4];
        f16x4 w1 = *(const f16x4*)&w2r[hq * 4 + 4];
        f16x2 p;
        p = __builtin_elementwise_max((f16x2){t00[0] + a0[0], t00[1] + a0[1]}, zero);
        acc0 = dot2_acc(p, (f16x2){w0[0], w0[1]}, acc0);
        p = __builtin_elementwise_max((f16x2){t00[2] + a0[2], t00[3] + a0[3]}, zero);
        acc0 = dot2_acc(p, (f16x2){w0[2], w0[3]}, acc0);
        p = __builtin_elementwise_max((f16x2){t01[0] + a1[0], t01[1] + a1[1]}, zero);
        acc0 = dot2_acc(p, (f16x2){w1[0], w1[1]}, acc0);
        p = __builtin_elementwise_max((f16x2){t01[2] + a1[2], t01[3] + a1[3]}, zero);
        acc0 = dot2_acc(p, (f16x2){w1[2], w1[3]}, acc0);
        p = __builtin_elementwise_max((f16x2){t10[0] + a0[0], t10[1] + a0[1]}, zero);
        acc1 = dot2_acc(p, (f16x2){w0[0], w0[1]}, acc1);
        p = __builtin_elementwise_max((f16x2){t10[2] + a0[2], t10[3] + a0[3]}, zero);
        acc1 = dot2_acc(p, (f16x2){w0[2], w0[3]}, acc1);
        p = __builtin_elementwise_max((f16x2){t11[0] + a1[0], t11[1] + a1[1]}, zero);
        acc1 = dot2_acc(p, (f16x2){w1[0], w1[1]}, acc1);
        p = __builtin_elementwise_max((f16x2){t11[2] + a1[2], t11[3] + a1[3]}, zero);
        acc1 = dot2_acc(p, (f16x2){w1[2], w1[3]}, acc1);
    }
    float* dst = lp + (size_t)(hc * 256 + bt0) * 512 + a;
    dst[0]   = acc0;
    dst[512] = acc1;
}

// ---------------------------------------------------------------------------
// combine: blocks [0,256): sum lp chunks + bias + monotonic, softmax -> out.
//          blocks [256,288): conv3 + GN2-fold + softplus -> durations.
// ---------------------------------------------------------------------------
__global__ __launch_bounds__(512) void combine_k(
    const float* __restrict__ lp, const float* __restrict__ b2,
    const bf16_t* __restrict__ y2, const float* __restrict__ stats2,
    const float* __restrict__ g, const float* __restrict__ bet,
    const float* __restrict__ w3, const float* __restrict__ b3,
    float* __restrict__ out)
{
    __shared__ float redm[8], redsum[8];
    const int bid = blockIdx.x;
    const int tid = threadIdx.x;
    if (bid < 256) {
        const int bt = bid, t = bt & 127;
        const int a = tid;
        const int lane = a & 63, wid = a >> 6;
        const size_t base = (size_t)bt * 512 + a;
        float v = lp[base] + lp[131072 + base] + lp[262144 + base] + lp[393216 + base];
        v += b2[0] - 0.1f * fabsf((float)a - 4.0f * (float)t);
        float m = v;
        #pragma unroll
        for (int off = 32; off > 0; off >>= 1) m = fmaxf(m, __shfl_xor(m, off));
        if (lane == 0) redm[wid] = m;
        __syncthreads();
        float M = redm[0];
        #pragma unroll
        for (int i = 1; i < 8; ++i) M = fmaxf(M, redm[i]);
        const float e = expf(v - M);
        float s = e;
        #pragma unroll
        for (int off = 32; off > 0; off >>= 1) s += __shfl_xor(s, off);
        if (lane == 0) redsum[wid] = s;
        __syncthreads();
        float S = redsum[0];
        #pragma unroll
        for (int i = 1; i < 8; ++i) S += redsum[i];
        out[(size_t)bt * 512 + a] = e * (1.0f / S);
    } else {
        const int lane = tid & 63, w = tid >> 6;
        const int bt = (bid - 256) * 8 + w;
        const int b = bt >> 7;
        const float cnt = 131072.f;
        const float mu = stats2[b * 2] / cnt;
        const float var = stats2[b * 2 + 1] / cnt - mu * mu;
        const float rs = rsqrtf(var + EPSV);
        const bf16_t* row = y2 + (size_t)bt * 1024 + lane * 16;
        float s1 = 0.f, s2 = 0.f, s3 = 0.f;
        #pragma unroll
        for (int c = 0; c < 2; ++c) {
            bf16x8 yv = *(const bf16x8*)(row + c * 8);
            #pragma unroll
            for (int j = 0; j < 8; ++j) {
                const int i = lane * 16 + c * 8 + j;
                const float gw = g[i] * w3[i];
                s1 += gw * (float)yv[j];
                s2 += gw;
                s3 += bet[i] * w3[i];
            }
        }
        #pragma unroll
        for (int off = 32; off > 0; off >>= 1) {
            s1 += __shfl_xor(s1, off);
            s2 += __shfl_xor(s2, off);
            s3 += __shfl_xor(s3, off);
        }
        if (lane == 0) {
            const float t = rs * (s1 - mu * s2) + s3 + b3[0];
            out[131072 + bt] = fmaxf(t, 0.f) + log1pf(expf(-fabsf(t)));
        }
    }
}

extern "C" void kernel_launch(void* const* d_in, const int* in_sizes, int n_in,
                              void* d_out, int out_size, void* d_ws, size_t ws_size,
                              hipStream_t stream) {
    const float* text   = (const float*)d_in[0];
    const float* audio  = (const float*)d_in[1];
    const float* a_w1   = (const float*)d_in[2];
    const float* a_b1   = (const float*)d_in[3];
    const float* a_w2   = (const float*)d_in[4];
    const float* a_b2   = (const float*)d_in[5];
    const float* d_w1   = (const float*)d_in[6];
    const float* d_b1   = (const float*)d_in[7];
    const float* gn1_g  = (const float*)d_in[8];
    const float* gn1_b  = (const float*)d_in[9];
    const float* d_w2   = (const float*)d_in[10];
    const float* d_b2   = (const float*)d_in[11];
    const float* gn2_g  = (const float*)d_in[12];
    const float* gn2_b  = (const float*)d_in[13];
    const float* d_w3   = (const float*)d_in[14];
    const float* d_b3   = (const float*)d_in[15];

    char* ws = (char*)d_ws;
    float* outf = (float*)d_out;

    bf16_t* text_bf  = (bf16_t*)(ws + OFF_TEXTBF);
    bf16_t* audio_bf = (bf16_t*)(ws + OFF_AUDIOBF);
    bf16_t* w1topT   = (bf16_t*)(ws + OFF_W1TOP);
    bf16_t* w1botT   = (bf16_t*)(ws + OFF_W1BOT);
    bf16_t* wc1      = (bf16_t*)(ws + OFF_WC1);
    bf16_t* wc2      = (bf16_t*)(ws + OFF_WC2);
    f16_t*  tp       = (f16_t*) (ws + OFF_TP);
    f16_t*  w2f      = (f16_t*) (ws + OFF_W2F);
    f16_t*  apT4     = (f16_t*) (ws + OFF_APT);
    bf16_t* xp0      = (bf16_t*)(ws + OFF_XP0);
    bf16_t* xp1      = (bf16_t*)(ws + OFF_XP1);
    bf16_t* y2       = (bf16_t*)(ws + OFF_Y2);
    float*  stats    = (float*) (ws + OFF_STATS);
    float*  lp       = (float*) (ws + OFF_LP);

    // 1: cvt activations + w1 transpose + conv weights + zero pads/stats + w2f
    prep_k<<<dim3(5377), 256, 0, stream>>>(text, audio, a_w1, d_w1, d_w2, a_w2,
                                           text_bf, xp0, audio_bf, w1topT, w1botT,
                                           wc1, wc2, xp1, stats, w2f);
    // 2: tp (f16, bias folded) + apT4 (f16 quad-packed) GEMMs, in-LDS split-k
    gemm_tpap_k<<<dim3(1280), 256, 0, stream>>>(text_bf, w1topT, a_b1, tp,
                                                audio_bf, w1botT, apT4);
    // 3: conv1 fused (8-wave split-k gemm + bias/relu + stats + transposed write)
    conv_fused_k<<<dim3(8, 64), 512, 0, stream>>>(wc1, xp0, d_b1, xp1, 130, 1, stats);
    // 4: GN1 apply
    gn_apply_k<<<dim3(256), 256, 0, stream>>>(xp1, stats, gn1_g, gn1_b);
    // 5: conv2 fused -> y2 (pre-GN2)
    conv_fused_k<<<dim3(8, 64), 512, 0, stream>>>(wc2, xp1, d_b2, y2, 128, 0, stats + 4);
    // 6: logits partials (2 t/block; packed f16 dot2)
    logits_k<<<dim3(128, 4), 512, 0, stream>>>(tp, apT4, w2f, lp);
    // 7: combine+softmax -> alignment; conv3+GN2fold+softplus -> durations
    combine_k<<<dim3(288), 512, 0, stream>>>(lp, a_b2, y2, stats + 4,
                                             gn2_g, gn2_b, d_w3, d_b3, outf);
}

// Round 10
// 193.722 us; speedup vs baseline: 1.2931x; 1.0382x over previous
//
#include <hip/hip_runtime.h>
#include <hip/hip_bf16.h>

// ---------------------------------------------------------------------------
// MonotonicAlignmentSearch R10: 5-dispatch graph (conv1 ∥ tp/ap GEMM fused;
// logits ∥ GN1 fused), logits 4-t-rows/block (apT traffic 64 MB).
// B=2, TT=128, TA=512, H=1024.
// ---------------------------------------------------------------------------

typedef __bf16 bf16_t;
typedef __bf16 bf16x8 __attribute__((ext_vector_type(8)));
typedef __bf16 bf16x4 __attribute__((ext_vector_type(4)));
typedef float  f32x4  __attribute__((ext_vector_type(4)));
typedef _Float16 f16_t;
typedef _Float16 f16x2 __attribute__((ext_vector_type(2)));
typedef _Float16 f16x4 __attribute__((ext_vector_type(4)));

#define EPSV 1e-5f

// ---- workspace offsets (bytes) — no overlays, ~26.2 MB << 256 MB ws -------
#define OFF_TEXTBF   0u          //  524288  bf16 text [256][1024]
#define OFF_AUDIOBF  524288u     // 2097152  bf16 audio [1024][1024]
#define OFF_W1TOP    2621440u    // 2097152  bf16 W1topT [1024][1024]
#define OFF_W1BOT    4718592u    // 2097152  bf16 W1botT [1024][1024]
#define OFF_WC1      6815744u    // 6291456  bf16 Wc1 [3][1024][1024]
#define OFF_WC2      13107200u   // 6291456  bf16 Wc2 [3][1024][1024]
#define OFF_TP       19398656u   //  524288  f16 tp [256][1024] (bias folded)
#define OFF_W2F      19922944u   //    2048  f16 w2 [1024]
#define OFF_APT      20447232u   // 2097152  f16 apT4 [256 hq][1024 ba][4]
#define OFF_XP0      22544384u   //  532480  bf16 xp0 [2][130][1024]
#define OFF_XP1      23076864u   //  532480  bf16 xp1 [2][130][1024]
#define OFF_Y2       23609344u   //  524288  bf16 y2 [256][1024] (pre-GN2)
#define OFF_STATS    24133632u   //      32  8 f32 GN stats
#define OFF_LP       24137728u   // 2097152  f32 lp [4 hc][256 bt][512 a]

// ---------------------------------------------------------------------------
// prep: [0,1280) cvt activations; [1280,3328) w1 transpose-cast;
// [3328,5376) conv-weight cvt; 5376: zero pads + stats + w2->f16.
// ---------------------------------------------------------------------------
__global__ __launch_bounds__(256) void prep_k(
    const float* __restrict__ text, const float* __restrict__ audio,
    const float* __restrict__ w1,
    const float* __restrict__ w1c, const float* __restrict__ w2c,
    const float* __restrict__ w2,
    bf16_t* __restrict__ text_bf, bf16_t* __restrict__ xp0,
    bf16_t* __restrict__ audio_bf,
    bf16_t* __restrict__ topT, bf16_t* __restrict__ botT,
    bf16_t* __restrict__ wc1, bf16_t* __restrict__ wc2,
    bf16_t* __restrict__ xp1, float* __restrict__ stats,
    f16_t* __restrict__ w2f)
{
    __shared__ float tile[32][33];
    const int bid = blockIdx.x;
    if (bid < 1280) {
        const int e = (bid * 256 + threadIdx.x) * 4;   // 1310720 total
        if (e < 262144) {
            float4 v = *(const float4*)&text[e];
            bf16x4 o; o[0] = (bf16_t)v.x; o[1] = (bf16_t)v.y; o[2] = (bf16_t)v.z; o[3] = (bf16_t)v.w;
            *(bf16x4*)&text_bf[e] = o;
            const int bt = e >> 10, h = e & 1023;
            const int b = bt >> 7, t = bt & 127;
            *(bf16x4*)&xp0[(size_t)(b * 130 + 1 + t) * 1024 + h] = o;
        } else {
            const int ea = e - 262144;
            float4 v = *(const float4*)&audio[ea];
            bf16x4 o; o[0] = (bf16_t)v.x; o[1] = (bf16_t)v.y; o[2] = (bf16_t)v.z; o[3] = (bf16_t)v.w;
            *(bf16x4*)&audio_bf[ea] = o;
        }
    } else if (bid < 3328) {
        const int b2 = bid - 1280;
        const int bx = b2 & 31, by = b2 >> 5;          // (32, 64)
        const int tx = threadIdx.x & 31, ty = threadIdx.x >> 5;
        #pragma unroll
        for (int j = 0; j < 4; ++j)
            tile[ty + j * 8][tx] = w1[(size_t)(by * 32 + ty + j * 8) * 1024 + bx * 32 + tx];
        __syncthreads();
        bf16_t* out = (by < 32) ? topT : botT;
        const int hbase = (by & 31) * 32;
        #pragma unroll
        for (int j = 0; j < 4; ++j) {
            const int d = bx * 32 + ty + j * 8;
            out[(size_t)d * 1024 + hbase + tx] = (bf16_t)tile[tx][ty + j * 8];
        }
    } else if (bid < 5376) {
        int b2 = bid - 3328;
        const float* w = (b2 < 1024) ? w1c : w2c;
        bf16_t* wc = (b2 < 1024) ? wc1 : wc2;
        b2 &= 1023;
        const int t = b2 * 256 + threadIdx.x;
        const int o = t >> 8, i4 = t & 255;
        const float* src = w + (size_t)o * 3072 + i4 * 12;
        float4 v0 = *(const float4*)&src[0];
        float4 v1 = *(const float4*)&src[4];
        float4 v2 = *(const float4*)&src[8];
        const float f[12] = {v0.x, v0.y, v0.z, v0.w, v1.x, v1.y, v1.z, v1.w, v2.x, v2.y, v2.z, v2.w};
        #pragma unroll
        for (int r = 0; r < 3; ++r) {
            bf16x4 o4;
            #pragma unroll
            for (int j = 0; j < 4; ++j) o4[j] = (bf16_t)f[j * 3 + r];
            *(bf16x4*)&wc[(size_t)r * 1048576 + (size_t)o * 1024 + i4 * 4] = o4;
        }
    } else {
        const int tid = threadIdx.x;
        const int rowmap[4] = {0, 129, 130, 259};
        const int f = tid * 16;
        const int r = f >> 10, w = f & 1023;
        bf16x8 z8 = (bf16x8)(bf16_t)0.0f;
        bf16_t* p0 = xp0 + (size_t)rowmap[r] * 1024 + w;
        bf16_t* p1 = xp1 + (size_t)rowmap[r] * 1024 + w;
        *(bf16x8*)p0 = z8; *(bf16x8*)(p0 + 8) = z8;
        *(bf16x8*)p1 = z8; *(bf16x8*)(p1 + 8) = z8;
        if (tid < 8) stats[tid] = 0.0f;
        float4 wv = *(const float4*)&w2[tid * 4];
        f16x4 wo; wo[0] = (f16_t)wv.x; wo[1] = (f16_t)wv.y; wo[2] = (f16_t)wv.z; wo[3] = (f16_t)wv.w;
        *(f16x4*)&w2f[tid * 4] = wo;
    }
}

// ---------------------------------------------------------------------------
// conv tile (16o x 32bt, 8 waves = i-chunks of 128, LDS split-k reduce,
// bias/relu + GN stats + bf16 transposed write). smem: 4608 floats.
// ---------------------------------------------------------------------------
__device__ __forceinline__ void conv_tile(
    const bf16_t* __restrict__ Wc, const bf16_t* __restrict__ xp,
    const float* __restrict__ bias, bf16_t* __restrict__ out,
    int rowsPerB, int rowOff, float* __restrict__ stats,
    int bx, int by, int tid, float* smem, float* sred, float* sredq)
{
    const int w = tid >> 6, l = tid & 63;
    const int bt0 = bx * 32, m0 = by * 16;
    const int i0 = w * 128;
    const int lm = l & 15, lk = (l >> 4) * 8;
    const int b = bt0 >> 7, tbase = bt0 & 127;
    f32x4 acc0 = (f32x4)(0.0f), acc1 = (f32x4)(0.0f);
    const bf16_t* aq = Wc + (size_t)(m0 + lm) * 1024 + i0 + lk;
    const bf16_t* bq = xp + (size_t)(b * 130 + tbase + lm) * 1024 + i0 + lk;
    #pragma unroll
    for (int r = 0; r < 3; ++r) {
        const bf16_t* ar = aq + (size_t)r * 1048576;
        const bf16_t* br = bq + (size_t)r * 1024;
        #pragma unroll
        for (int kk = 0; kk < 128; kk += 32) {
            bf16x8 af = *(const bf16x8*)(ar + kk);
            bf16x8 bf0 = *(const bf16x8*)(br + kk);
            bf16x8 bf1 = *(const bf16x8*)(br + 16384 + kk);
            acc0 = __builtin_amdgcn_mfma_f32_16x16x32_bf16(af, bf0, acc0, 0, 0, 0);
            acc1 = __builtin_amdgcn_mfma_f32_16x16x32_bf16(af, bf1, acc1, 0, 0, 0);
        }
    }
    {
        const int row = (l >> 4) * 4;
        #pragma unroll
        for (int r = 0; r < 4; ++r) {
            smem[w * 576 + (row + r) * 36 + lm] = acc0[r];
            smem[w * 576 + (row + r) * 36 + 16 + lm] = acc1[r];
        }
    }
    __syncthreads();
    const int m = tid >> 5, n = tid & 31;
    float v = 0.f;
    #pragma unroll
    for (int ww = 0; ww < 8; ++ww) v += smem[ww * 576 + m * 36 + n];
    v = fmaxf(v + bias[m0 + m], 0.f);
    float s = v, q = v * v;
    __syncthreads();
    smem[m * 36 + n] = v;
    #pragma unroll
    for (int off = 32; off > 0; off >>= 1) {
        s += __shfl_xor(s, off);
        q += __shfl_xor(q, off);
    }
    if (l == 0) { sred[w] = s; sredq[w] = q; }
    __syncthreads();
    if (tid == 0) {
        float ts = 0.f, tq = 0.f;
        #pragma unroll
        for (int ww = 0; ww < 8; ++ww) { ts += sred[ww]; tq += sredq[ww]; }
        atomicAdd(&stats[b * 2], ts);
        atomicAdd(&stats[b * 2 + 1], tq);
    }
    if (tid < 64) {
        const int row = tid >> 1, half = tid & 1;
        bf16x8 o8;
        #pragma unroll
        for (int j = 0; j < 8; ++j) o8[j] = (bf16_t)smem[(half * 8 + j) * 36 + row];
        const int t = tbase + row;
        *(bf16x8*)&out[(size_t)(b * rowsPerB + rowOff + t) * 1024 + m0 + half * 8] = o8;
    }
}

// ---------------------------------------------------------------------------
// tp/ap GEMM unit: 256 threads, 32x32 tile, 4-way k-split, LDS reduce.
// unit < 256: tp tile; else apT4 quad-packed tile. base: 4608 floats.
// ---------------------------------------------------------------------------
__device__ __forceinline__ void gemm_unit(
    int unit, int ut, float* base,
    const bf16_t* __restrict__ text_bf, const bf16_t* __restrict__ w1topT,
    const float* __restrict__ b1, f16_t* __restrict__ tp,
    const bf16_t* __restrict__ audio_bf, const bf16_t* __restrict__ w1botT,
    f16_t* __restrict__ apT4)
{
    const int is_tp = (unit < 256) ? 1 : 0;
    const int b2 = is_tp ? unit : unit - 256;
    const int n0 = (b2 & 31) * 32, m0 = (b2 >> 5) * 32;
    const int w = ut >> 6, l = ut & 63;
    const int lm = l & 15, lk = (l >> 4) * 8;
    const int k0 = w * 256;
    const bf16_t* A  = is_tp ? text_bf : audio_bf;
    const bf16_t* Bt = is_tp ? w1topT : w1botT;
    f32x4 acc[2][2];
    #pragma unroll
    for (int mt = 0; mt < 2; ++mt)
        #pragma unroll
        for (int nt = 0; nt < 2; ++nt) acc[mt][nt] = (f32x4)(0.0f);
    const bf16_t* Ap = A + (size_t)(m0 + lm) * 1024 + k0 + lk;
    const bf16_t* Bp = Bt + (size_t)(n0 + lm) * 1024 + k0 + lk;
    #pragma unroll
    for (int kk = 0; kk < 256; kk += 32) {
        bf16x8 af[2], bfr[2];
        #pragma unroll
        for (int i = 0; i < 2; ++i) af[i] = *(const bf16x8*)(Ap + (size_t)i * 16384 + kk);
        #pragma unroll
        for (int i = 0; i < 2; ++i) bfr[i] = *(const bf16x8*)(Bp + (size_t)i * 16384 + kk);
        #pragma unroll
        for (int mt = 0; mt < 2; ++mt)
            #pragma unroll
            for (int nt = 0; nt < 2; ++nt)
                acc[mt][nt] = __builtin_amdgcn_mfma_f32_16x16x32_bf16(af[mt], bfr[nt], acc[mt][nt], 0, 0, 0);
    }
    #pragma unroll
    for (int mt = 0; mt < 2; ++mt) {
        const int row = mt * 16 + (l >> 4) * 4;
        #pragma unroll
        for (int nt = 0; nt < 2; ++nt)
            #pragma unroll
            for (int r = 0; r < 4; ++r)
                base[w * 1152 + (row + r) * 36 + nt * 16 + lm] = acc[mt][nt][r];
    }
    __syncthreads();
    if (is_tp) {
        const int m = ut >> 3, n4 = (ut & 7) * 4;
        f16x4 v;
        #pragma unroll
        for (int j = 0; j < 4; ++j)
            v[j] = (f16_t)(base[m * 36 + n4 + j] + base[1152 + m * 36 + n4 + j]
                         + base[2304 + m * 36 + n4 + j] + base[3456 + m * 36 + n4 + j]
                         + b1[n0 + n4 + j]);
        *(f16x4*)&tp[(size_t)(m0 + m) * 1024 + n0 + n4] = v;
    } else {
        const int a = ut >> 3, q = ut & 7;
        const int b = m0 >> 9, a0 = m0 & 511;
        f16x4 v;
        #pragma unroll
        for (int c = 0; c < 4; ++c)
            v[c] = (f16_t)(base[a * 36 + q * 4 + c] + base[1152 + a * 36 + q * 4 + c]
                         + base[2304 + a * 36 + q * 4 + c] + base[3456 + a * 36 + q * 4 + c]);
        const size_t hq = (size_t)(n0 >> 2) + q;
        *(f16x4*)&apT4[(hq * 1024 + b * 512 + a0 + a) * 4] = v;
    }
}

// ---------------------------------------------------------------------------
// P2: blocks [0,512) conv1 tiles; [512,1152) two gemm units each (1280 units).
// ---------------------------------------------------------------------------
__global__ __launch_bounds__(512, 4) void p2_k(
    const bf16_t* __restrict__ wc1, const bf16_t* __restrict__ xp0,
    const float* __restrict__ d_b1, bf16_t* __restrict__ xp1,
    float* __restrict__ stats,
    const bf16_t* __restrict__ text_bf, const bf16_t* __restrict__ w1topT,
    const float* __restrict__ a_b1, f16_t* __restrict__ tp,
    const bf16_t* __restrict__ audio_bf, const bf16_t* __restrict__ w1botT,
    f16_t* __restrict__ apT4)
{
    __shared__ float smem[9216];
    __shared__ float sred[8], sredq[8];
    const int bid = blockIdx.x;
    const int tid = threadIdx.x;
    if (bid < 512) {
        conv_tile(wc1, xp0, d_b1, xp1, 130, 1, stats,
                  bid & 7, bid >> 3, tid, smem, sred, sredq);
    } else {
        const int unit = (bid - 512) * 2 + (tid >> 8);
        gemm_unit(unit, tid & 255, smem + (tid >> 8) * 4608,
                  text_bf, w1topT, a_b1, tp, audio_bf, w1botT, apT4);
    }
}

// ---------------------------------------------------------------------------
// P3: blocks [0,256) logits 4-t tiles; [256,384) GN1-apply chunks.
// ---------------------------------------------------------------------------
__device__ __forceinline__ float dot2_acc(f16x2 x, f16x2 w, float acc) {
#if __has_builtin(__builtin_amdgcn_fdot2)
    return __builtin_amdgcn_fdot2(x, w, acc, false);
#else
    return acc + (float)x[0] * (float)w[0] + (float)x[1] * (float)w[1];
#endif
}

__global__ __launch_bounds__(512) void p3_k(
    const f16_t* __restrict__ tp, const f16_t* __restrict__ apT4,
    const f16_t* __restrict__ w2f, float* __restrict__ lp,
    bf16_t* __restrict__ xp1, const float* __restrict__ stats,
    const float* __restrict__ g, const float* __restrict__ bet)
{
    const int bid = blockIdx.x;
    const int tid = threadIdx.x;
    if (bid < 256) {
        const int btp = bid & 63, hc = bid >> 6;
        const int bt0 = btp * 4;
        const int b = bt0 >> 7;
        const int a = tid;
        const f16_t* tpr = tp + (size_t)bt0 * 1024 + hc * 256;   // wave-uniform
        const f16_t* w2r = w2f + hc * 256;
        const f16_t* apc = apT4 + ((size_t)(hc * 64) * 1024 + b * 512 + a) * 4;
        float acc[4] = {0.f, 0.f, 0.f, 0.f};
        const f16x2 zero = (f16x2)(f16_t)0.0f;
        #pragma unroll 2
        for (int hq = 0; hq < 64; hq += 2) {                    // 8 h per iter
            f16x4 a0 = *(const f16x4*)(apc + (size_t)hq * 4096);
            f16x4 a1 = *(const f16x4*)(apc + (size_t)(hq + 1) * 4096);
            f16x4 w0 = *(const f16x4*)&w2r[hq * 4];
            f16x4 w1 = *(const f16x4*)&w2r[hq * 4 + 4];
            #pragma unroll
            for (int r = 0; r < 4; ++r) {
                f16x4 t0 = *(const f16x4*)&tpr[r * 1024 + hq * 4];
                f16x4 t1 = *(const f16x4*)&tpr[r * 1024 + hq * 4 + 4];
                f16x2 p;
                p = __builtin_elementwise_max((f16x2){t0[0] + a0[0], t0[1] + a0[1]}, zero);
                acc[r] = dot2_acc(p, (f16x2){w0[0], w0[1]}, acc[r]);
                p = __builtin_elementwise_max((f16x2){t0[2] + a0[2], t0[3] + a0[3]}, zero);
                acc[r] = dot2_acc(p, (f16x2){w0[2], w0[3]}, acc[r]);
                p = __builtin_elementwise_max((f16x2){t1[0] + a1[0], t1[1] + a1[1]}, zero);
                acc[r] = dot2_acc(p, (f16x2){w1[0], w1[1]}, acc[r]);
                p = __builtin_elementwise_max((f16x2){t1[2] + a1[2], t1[3] + a1[3]}, zero);
                acc[r] = dot2_acc(p, (f16x2){w1[2], w1[3]}, acc[r]);
            }
        }
        float* dst = lp + (size_t)(hc * 256 + bt0) * 512 + a;
        #pragma unroll
        for (int r = 0; r < 4; ++r) dst[(size_t)r * 512] = acc[r];
    } else {
        // GN1 apply in-place on padded xp1
        const int idx4 = (bid - 256) * 512 + tid;   // 65536 total
        const int e = idx4 * 4;
        const int bt = e >> 10, o = e & 1023;
        const int b = bt >> 7, t = bt & 127;
        bf16_t* p = xp1 + (size_t)(b * 130 + 1 + t) * 1024 + o;
        const float cnt = 131072.f;
        const float mu = stats[b * 2] / cnt;
        const float var = stats[b * 2 + 1] / cnt - mu * mu;
        const float rs = rsqrtf(var + EPSV);
        bf16x4 v = *(bf16x4*)p;
        float4 gv = *(const float4*)&g[o];
        float4 bv = *(const float4*)&bet[o];
        bf16x4 ov;
        ov[0] = (bf16_t)(((float)v[0] - mu) * rs * gv.x + bv.x);
        ov[1] = (bf16_t)(((float)v[1] - mu) * rs * gv.y + bv.y);
        ov[2] = (bf16_t)(((float)v[2] - mu) * rs * gv.z + bv.z);
        ov[3] = (bf16_t)(((float)v[3] - mu) * rs * gv.w + bv.w);
        *(bf16x4*)p = ov;
    }
}

// conv2 standalone (512 blocks)
__global__ __launch_bounds__(512, 4) void conv2_k(
    const bf16_t* __restrict__ wc2, const bf16_t* __restrict__ xp1,
    const float* __restrict__ d_b2, bf16_t* __restrict__ y2,
    float* __restrict__ stats2)
{
    __shared__ float smem[4608];
    __shared__ float sred[8], sredq[8];
    conv_tile(wc2, xp1, d_b2, y2, 128, 0, stats2,
              blockIdx.x & 7, blockIdx.x >> 3, threadIdx.x, smem, sred, sredq);
}

// ---------------------------------------------------------------------------
// combine: blocks [0,256): sum lp chunks + bias + monotonic, softmax -> out.
//          blocks [256,288): conv3 + GN2-fold + softplus -> durations.
// ---------------------------------------------------------------------------
__global__ __launch_bounds__(512) void combine_k(
    const float* __restrict__ lp, const float* __restrict__ b2,
    const bf16_t* __restrict__ y2, const float* __restrict__ stats2,
    const float* __restrict__ g, const float* __restrict__ bet,
    const float* __restrict__ w3, const float* __restrict__ b3,
    float* __restrict__ out)
{
    __shared__ float redm[8], redsum[8];
    const int bid = blockIdx.x;
    const int tid = threadIdx.x;
    if (bid < 256) {
        const int bt = bid, t = bt & 127;
        const int a = tid;
        const int lane = a & 63, wid = a >> 6;
        const size_t base = (size_t)bt * 512 + a;
        float v = lp[base] + lp[131072 + base] + lp[262144 + base] + lp[393216 + base];
        v += b2[0] - 0.1f * fabsf((float)a - 4.0f * (float)t);
        float m = v;
        #pragma unroll
        for (int off = 32; off > 0; off >>= 1) m = fmaxf(m, __shfl_xor(m, off));
        if (lane == 0) redm[wid] = m;
        __syncthreads();
        float M = redm[0];
        #pragma unroll
        for (int i = 1; i < 8; ++i) M = fmaxf(M, redm[i]);
        const float e = expf(v - M);
        float s = e;
        #pragma unroll
        for (int off = 32; off > 0; off >>= 1) s += __shfl_xor(s, off);
        if (lane == 0) redsum[wid] = s;
        __syncthreads();
        float S = redsum[0];
        #pragma unroll
        for (int i = 1; i < 8; ++i) S += redsum[i];
        out[(size_t)bt * 512 + a] = e * (1.0f / S);
    } else {
        const int lane = tid & 63, w = tid >> 6;
        const int bt = (bid - 256) * 8 + w;
        const int b = bt >> 7;
        const float cnt = 131072.f;
        const float mu = stats2[b * 2] / cnt;
        const float var = stats2[b * 2 + 1] / cnt - mu * mu;
        const float rs = rsqrtf(var + EPSV);
        const bf16_t* row = y2 + (size_t)bt * 1024 + lane * 16;
        float s1 = 0.f, s2 = 0.f, s3 = 0.f;
        #pragma unroll
        for (int c = 0; c < 2; ++c) {
            bf16x8 yv = *(const bf16x8*)(row + c * 8);
            #pragma unroll
            for (int j = 0; j < 8; ++j) {
                const int i = lane * 16 + c * 8 + j;
                const float gw = g[i] * w3[i];
                s1 += gw * (float)yv[j];
                s2 += gw;
                s3 += bet[i] * w3[i];
            }
        }
        #pragma unroll
        for (int off = 32; off > 0; off >>= 1) {
            s1 += __shfl_xor(s1, off);
            s2 += __shfl_xor(s2, off);
            s3 += __shfl_xor(s3, off);
        }
        if (lane == 0) {
            const float t = rs * (s1 - mu * s2) + s3 + b3[0];
            out[131072 + bt] = fmaxf(t, 0.f) + log1pf(expf(-fabsf(t)));
        }
    }
}

extern "C" void kernel_launch(void* const* d_in, const int* in_sizes, int n_in,
                              void* d_out, int out_size, void* d_ws, size_t ws_size,
                              hipStream_t stream) {
    const float* text   = (const float*)d_in[0];
    const float* audio  = (const float*)d_in[1];
    const float* a_w1   = (const float*)d_in[2];
    const float* a_b1   = (const float*)d_in[3];
    const float* a_w2   = (const float*)d_in[4];
    const float* a_b2   = (const float*)d_in[5];
    const float* d_w1   = (const float*)d_in[6];
    const float* d_b1   = (const float*)d_in[7];
    const float* gn1_g  = (const float*)d_in[8];
    const float* gn1_b  = (const float*)d_in[9];
    const float* d_w2   = (const float*)d_in[10];
    const float* d_b2   = (const float*)d_in[11];
    const float* gn2_g  = (const float*)d_in[12];
    const float* gn2_b  = (const float*)d_in[13];
    const float* d_w3   = (const float*)d_in[14];
    const float* d_b3   = (const float*)d_in[15];

    char* ws = (char*)d_ws;
    float* outf = (float*)d_out;

    bf16_t* text_bf  = (bf16_t*)(ws + OFF_TEXTBF);
    bf16_t* audio_bf = (bf16_t*)(ws + OFF_AUDIOBF);
    bf16_t* w1topT   = (bf16_t*)(ws + OFF_W1TOP);
    bf16_t* w1botT   = (bf16_t*)(ws + OFF_W1BOT);
    bf16_t* wc1      = (bf16_t*)(ws + OFF_WC1);
    bf16_t* wc2      = (bf16_t*)(ws + OFF_WC2);
    f16_t*  tp       = (f16_t*) (ws + OFF_TP);
    f16_t*  w2f      = (f16_t*) (ws + OFF_W2F);
    f16_t*  apT4     = (f16_t*) (ws + OFF_APT);
    bf16_t* xp0      = (bf16_t*)(ws + OFF_XP0);
    bf16_t* xp1      = (bf16_t*)(ws + OFF_XP1);
    bf16_t* y2       = (bf16_t*)(ws + OFF_Y2);
    float*  stats    = (float*) (ws + OFF_STATS);
    float*  lp       = (float*) (ws + OFF_LP);

    // 1: prep (cvt activations, w1 transpose, conv weights, pads/stats, w2f)
    prep_k<<<dim3(5377), 256, 0, stream>>>(text, audio, a_w1, d_w1, d_w2, a_w2,
                                           text_bf, xp0, audio_bf, w1topT, w1botT,
                                           wc1, wc2, xp1, stats, w2f);
    // 2: conv1 (blocks 0..511) ∥ tp/ap GEMM (blocks 512..1151, 1280 units)
    p2_k<<<dim3(1152), 512, 0, stream>>>(wc1, xp0, d_b1, xp1, stats,
                                         text_bf, w1topT, a_b1, tp,
                                         audio_bf, w1botT, apT4);
    // 3: logits partials (blocks 0..255, 4 t/block) ∥ GN1 apply (256..383)
    p3_k<<<dim3(384), 512, 0, stream>>>(tp, apT4, w2f, lp,
                                        xp1, stats, gn1_g, gn1_b);
    // 4: conv2 -> y2 (pre-GN2)
    conv2_k<<<dim3(512), 512, 0, stream>>>(wc2, xp1, d_b2, y2, stats + 4);
    // 5: combine+softmax -> alignment; conv3+GN2fold+softplus -> durations
    combine_k<<<dim3(288), 512, 0, stream>>>(lp, a_b2, y2, stats + 4,
                                             gn2_g, gn2_b, d_w3, d_b3, outf);
}